// Round 4
// baseline (315.202 us; speedup 1.0000x reference)
//
#include <hip/hip_runtime.h>

#define B_ 8
#define N_ 1568
#define NPAD_ 1600
#define C_ 384
#define H_ 6
#define D_ 64
#define BH_ 48
#define SZ_ (B_*H_*N_*D_)
#define EPS_ 1e-6f
#define CSC_ 0.18033688011112042f  /* D^-0.5 * log2(e) */

typedef short s16x8 __attribute__((ext_vector_type(8)));
typedef short s16x4 __attribute__((ext_vector_type(4)));
typedef float f32x4 __attribute__((ext_vector_type(4)));

static __device__ __forceinline__ ushort f2bf(float f){
  union { float f; unsigned u; } v; v.f = f;
  unsigned r = v.u + 0x7fffu + ((v.u >> 16) & 1u);
  return (ushort)(r >> 16);
}
static __device__ __forceinline__ unsigned cvtpk(float lo, float hi){
  unsigned r;
  asm("v_cvt_pk_bf16_f32 %0, %1, %2" : "=v"(r) : "v"(lo), "v"(hi));
  return r;
}
#define MFMA16(a,b,c) __builtin_amdgcn_mfma_f32_16x16x32_bf16((a),(b),(c),0,0,0)

#if __has_builtin(__builtin_amdgcn_exp2f)
#define EXP2F(x) __builtin_amdgcn_exp2f(x)
#else
#define EXP2F(x) exp2f(x)
#endif

// ---------------- policy pad: per-batch stride NPAD_, zeros for n in [N_, NPAD_) ----------------
#define POLPAD_ (B_*NPAD_)
__global__ __launch_bounds__(256) void pol_pad_k(const float* __restrict__ vis, float* __restrict__ pp){
  int i = blockIdx.x*256 + threadIdx.x;
  if (i < POLPAD_){
    int b = i / NPAD_, n = i - b*NPAD_;
    pp[i] = (n < N_) ? vis[b*N_ + n] : 0.f;
  }
}

// ---------------- convert f32 -> bf16 for X, w_qkv, w_proj in one launch ----------------
#define XV8_ 602112   /* 12544*384/8 */
#define WQ8_ 55296    /* 1152*384/8 */
#define WP8_ 18432    /* 384*384/8  */
__global__ __launch_bounds__(256) void cvt_all(const float* __restrict__ X, const float* __restrict__ Wq,
                                               const float* __restrict__ Wp, ushort* __restrict__ Xb,
                                               ushort* __restrict__ Wqb, ushort* __restrict__ Wpb){
  int i = blockIdx.x*256 + threadIdx.x;
  const float* src; ushort* dst; int off;
  if (i < XV8_)            { src = X;  dst = Xb;  off = i; }
  else if (i < XV8_+WQ8_)  { src = Wq; dst = Wqb; off = i - XV8_; }
  else                     { src = Wp; dst = Wpb; off = i - XV8_ - WQ8_; }
  float4 a = ((const float4*)src)[off*2];
  float4 b = ((const float4*)src)[off*2+1];
  s16x8 r;
  r[0]=(short)f2bf(a.x); r[1]=(short)f2bf(a.y); r[2]=(short)f2bf(a.z); r[3]=(short)f2bf(a.w);
  r[4]=(short)f2bf(b.x); r[5]=(short)f2bf(b.y); r[6]=(short)f2bf(b.z); r[7]=(short)f2bf(b.w);
  *(s16x8*)&dst[off*8] = r;
}

// ---------------- QKV GEMM (bf16, LDS-staged): qkv = Xb @ Wqb^T -> Q, K, V^T ----------------
__global__ __launch_bounds__(256) void qkv_gemm(const ushort* __restrict__ Xb, const ushort* __restrict__ Wb,
                                                ushort* __restrict__ Qg, ushort* __restrict__ Kg,
                                                ushort* __restrict__ Vtg){
  __shared__ __align__(16) ushort Al[128*40];
  __shared__ __align__(16) ushort Bl[64*40];
  const int tid = threadIdx.x, lane = tid&63, w = tid>>6;
  const int g = lane>>4, lr = lane&15;
  const int wr = w>>1, wc = w&1;
  const int m0 = blockIdx.x*128, j0 = blockIdx.y*64;
  const int ar = tid>>1, ah = tid&1;
  const int br = tid>>2, bq = tid&3;
  f32x4 acc[4][2];
  #pragma unroll
  for (int i=0;i<4;i++){ acc[i][0]=(f32x4){0,0,0,0}; acc[i][1]=(f32x4){0,0,0,0}; }

  for (int ks=0; ks<384; ks+=32){
    const ushort* as = Xb + (size_t)(m0+ar)*384 + ks + ah*16;
    s16x8 a0 = ((const s16x8*)as)[0];
    s16x8 a1 = ((const s16x8*)as)[1];
    s16x8 b0 = *(const s16x8*)(Wb + (size_t)(j0+br)*384 + ks + bq*8);
    *(s16x8*)&Al[ar*40 + ah*16]     = a0;
    *(s16x8*)&Al[ar*40 + ah*16 + 8] = a1;
    *(s16x8*)&Bl[br*40 + bq*8]      = b0;
    __syncthreads();
    s16x8 af[4], bf[2];
    #pragma unroll
    for (int fm=0; fm<4; fm++) af[fm] = *(const s16x8*)&Al[(wr*64+fm*16+lr)*40 + g*8];
    #pragma unroll
    for (int fn=0; fn<2; fn++) bf[fn] = *(const s16x8*)&Bl[(wc*32+fn*16+lr)*40 + g*8];
    #pragma unroll
    for (int fm=0; fm<4; fm++)
      #pragma unroll
      for (int fn=0; fn<2; fn++)
        acc[fm][fn] = MFMA16(af[fm], bf[fn], acc[fm][fn]);
    __syncthreads();
  }
  const int t = j0/384, h = (j0%384)/64;
  #pragma unroll
  for (int fm=0; fm<4; fm++){
    #pragma unroll
    for (int jj=0; jj<4; jj++){
      int m = m0 + wr*64 + fm*16 + g*4 + jj;
      int bi = m / N_; int n = m - bi*N_;
      #pragma unroll
      for (int fn=0; fn<2; fn++){
        int d = wc*32 + fn*16 + lr;
        float v = acc[fm][fn][jj];
        if (t==0)      Qg[((size_t)(bi*H_+h)*N_ + n)*64 + d] = f2bf(v * CSC_);
        else if (t==1) Kg[((size_t)(bi*H_+h)*N_ + n)*64 + d] = f2bf(v);
        else           Vtg[((size_t)(bi*H_+h)*64 + d)*N_ + n] = f2bf(v);
      }
    }
  }
}

// ---------------- fused flash attention: no LDS, no barriers, direct-global fragments ----------------
__global__ __launch_bounds__(256,4) void attn_fwd(const ushort* __restrict__ Qg, const ushort* __restrict__ Kg,
                                                  const ushort* __restrict__ Vt, const float* __restrict__ pol,
                                                  ushort* __restrict__ AO){
  const int tid = threadIdx.x, lane = tid&63, w = tid>>6;
  const int g = lane>>4, lr = lane&15;
  const int bh = blockIdx.x; const int b = bh / H_, h = bh - b*H_;
  const int qrow0 = blockIdx.y*64 + w*16;
  const int q = qrow0 + lr;
  const int qc = q < N_ ? q : N_-1;
  const ushort* Qrow = Qg + ((size_t)bh*N_ + qc)*64;
  const s16x8 qf0 = *(const s16x8*)(Qrow + g*8);
  const s16x8 qf1 = *(const s16x8*)(Qrow + 32 + g*8);
  const float* polp = pol + b*NPAD_;     // per-batch padded: keys >= N_ read 0.0
  const ushort* Kbh = Kg + (size_t)bh*N_*64;
  const ushort* Vbh = Vt + (size_t)bh*64*N_;
  const int sl0 = ((lane>>4)&1)<<5 | lr;   // bpermute source lanes
  const int sl1 = sl0 + 16;

  f32x4 o[4];
  #pragma unroll
  for (int i=0;i<4;i++) o[i] = (f32x4){0,0,0,0};
  float M = -INFINITY, L = 0.f;

  for (int t0=0; t0<N_; t0+=64){
    // ---- K fragments direct from global (rows clamped; OOB keys masked by zero policy) ----
    s16x8 kf0[4], kf1[4];
    #pragma unroll
    for (int kg=0; kg<4; kg++){
      int krow = t0 + kg*16 + lr; krow = krow < N_ ? krow : N_-1;
      const ushort* kp = Kbh + (size_t)krow*64;
      kf0[kg] = *(const s16x8*)(kp + g*8);
      kf1[kg] = *(const s16x8*)(kp + 32 + g*8);
    }
    // ---- policy (per-batch padded: OOB keys read 0.0) ----
    float4 pmv[4];
    #pragma unroll
    for (int kg=0; kg<4; kg++) pmv[kg] = *(const float4*)&polp[t0 + kg*16 + 4*g];

    // ---- S^T = K Q^T : st[kg][jj] = logit(q=qrow0+lr, key=t0+kg*16+4g+jj), log2-scaled ----
    f32x4 st[4];
    #pragma unroll
    for (int kg=0; kg<4; kg++){
      f32x4 z = (f32x4){0,0,0,0};
      z = MFMA16(kf0[kg], qf0, z);
      st[kg] = MFMA16(kf1[kg], qf1, z);
    }

    // ---- online softmax (per-lane row q), defer-max THR=8 ----
    float pmax;
    {
      float m0 = fmaxf(fmaxf(st[0][0],st[0][1]), fmaxf(st[0][2],st[0][3]));
      float m1 = fmaxf(fmaxf(st[1][0],st[1][1]), fmaxf(st[1][2],st[1][3]));
      float m2 = fmaxf(fmaxf(st[2][0],st[2][1]), fmaxf(st[2][2],st[2][3]));
      float m3 = fmaxf(fmaxf(st[3][0],st[3][1]), fmaxf(st[3][2],st[3][3]));
      pmax = fmaxf(fmaxf(m0,m1), fmaxf(m2,m3));
      pmax = fmaxf(pmax, __shfl_xor(pmax, 16));
      pmax = fmaxf(pmax, __shfl_xor(pmax, 32));
    }
    if (__any(pmax > M + 8.f)){
      float Mn = fmaxf(M, pmax);
      float corr = EXP2F(M - Mn);
      L *= corr;
      #pragma unroll
      for (int fd=0; fd<4; fd++){ o[fd][0]*=corr; o[fd][1]*=corr; o[fd][2]*=corr; o[fd][3]*=corr; }
      M = Mn;
    }
    const bool dg = (qrow0 & ~63) == t0;   // diagonal lives in this tile
    #pragma unroll
    for (int kg=0; kg<4; kg++){
      float4 pmvk = pmv[kg];
      if (dg){
        #pragma unroll
        for (int jj=0; jj<4; jj++){
          float e = EXP2F(st[kg][jj] - M);
          float em = e * ((&pmvk.x)[jj]);
          int key = t0 + kg*16 + 4*g + jj;
          st[kg][jj] = (key == q) ? e : em;
        }
      } else {
        #pragma unroll
        for (int jj=0; jj<4; jj++){
          float e = EXP2F(st[kg][jj] - M);
          st[kg][jj] = e * ((&pmvk.x)[jj]);
        }
      }
    }
    {
      float se = (st[0][0]+st[0][1]) + (st[0][2]+st[0][3]);
      se += (st[1][0]+st[1][1]) + (st[1][2]+st[1][3]);
      se += (st[2][0]+st[2][1]) + (st[2][2]+st[2][3]);
      se += (st[3][0]+st[3][1]) + (st[3][2]+st[3][3]);
      se += __shfl_xor(se, 16);
      se += __shfl_xor(se, 32);
      L += se;
    }

    // ---- pack P to bf16 pairs, redistribute to B-fragments via bpermute ----
    unsigned pk[4][2];
    #pragma unroll
    for (int kg=0; kg<4; kg++){
      pk[kg][0] = cvtpk(st[kg][0], st[kg][1]);
      pk[kg][1] = cvtpk(st[kg][2], st[kg][3]);
    }
    union { unsigned u[4]; s16x8 v; } bfr[2];
    #pragma unroll
    for (int kh=0; kh<2; kh++){
      #pragma unroll
      for (int wd=0; wd<4; wd++){
        int srcl = (wd < 2) ? sl0 : sl1;
        unsigned a0 = (unsigned)__shfl((int)pk[2*kh][wd&1],   srcl);
        unsigned a1 = (unsigned)__shfl((int)pk[2*kh+1][wd&1], srcl);
        bfr[kh].u[wd] = (g < 2) ? a0 : a1;
      }
    }

    // ---- O^T += V^T P^T, V^T fragments direct from global ----
    #pragma unroll
    for (int fd=0; fd<4; fd++){
      const ushort* vrow = Vbh + (size_t)(fd*16+lr)*N_ + t0;
      s16x8 va0 = *(const s16x8*)(vrow + g*8);
      s16x8 va1 = *(const s16x8*)(vrow + 32 + g*8);
      o[fd] = MFMA16(va0, bfr[0].v, o[fd]);
      o[fd] = MFMA16(va1, bfr[1].v, o[fd]);
    }
  }

  // ---- epilogue: normalize, write AO[b,q, h*64 + d] (d = fd*16+4g+jj) ----
  if (q < N_){
    float inv = 1.f / (L + EPS_);
    ushort* aop = AO + ((size_t)b*N_ + q)*C_ + h*64 + 4*g;
    #pragma unroll
    for (int fd=0; fd<4; fd++){
      s16x4 r;
      r[0]=(short)f2bf(o[fd][0]*inv); r[1]=(short)f2bf(o[fd][1]*inv);
      r[2]=(short)f2bf(o[fd][2]*inv); r[3]=(short)f2bf(o[fd][3]*inv);
      *(s16x4*)(aop + fd*16) = r;
    }
  }
}

// ---------------- proj GEMM (bf16, LDS-staged): out = AO @ Wpb^T + b, f32 out ----------------
__global__ __launch_bounds__(256) void proj_gemm(const ushort* __restrict__ A, const ushort* __restrict__ Wb,
                                                 const float* __restrict__ bias, float* __restrict__ out){
  __shared__ __align__(16) ushort Al[128*40];
  __shared__ __align__(16) ushort Bl[64*40];
  const int tid = threadIdx.x, lane = tid&63, w = tid>>6;
  const int g = lane>>4, lr = lane&15;
  const int wr = w>>1, wc = w&1;
  const int m0 = blockIdx.x*128, j0 = blockIdx.y*64;
  const int ar = tid>>1, ah = tid&1;
  const int br = tid>>2, bq = tid&3;
  f32x4 acc[4][2];
  #pragma unroll
  for (int i=0;i<4;i++){ acc[i][0]=(f32x4){0,0,0,0}; acc[i][1]=(f32x4){0,0,0,0}; }

  for (int ks=0; ks<384; ks+=32){
    const ushort* as = A + (size_t)(m0+ar)*384 + ks + ah*16;
    s16x8 a0 = ((const s16x8*)as)[0];
    s16x8 a1 = ((const s16x8*)as)[1];
    s16x8 b0 = *(const s16x8*)(Wb + (size_t)(j0+br)*384 + ks + bq*8);
    *(s16x8*)&Al[ar*40 + ah*16]     = a0;
    *(s16x8*)&Al[ar*40 + ah*16 + 8] = a1;
    *(s16x8*)&Bl[br*40 + bq*8]      = b0;
    __syncthreads();
    s16x8 af[4], bf[2];
    #pragma unroll
    for (int fm=0; fm<4; fm++) af[fm] = *(const s16x8*)&Al[(wr*64+fm*16+lr)*40 + g*8];
    #pragma unroll
    for (int fn=0; fn<2; fn++) bf[fn] = *(const s16x8*)&Bl[(wc*32+fn*16+lr)*40 + g*8];
    #pragma unroll
    for (int fm=0; fm<4; fm++)
      #pragma unroll
      for (int fn=0; fn<2; fn++)
        acc[fm][fn] = MFMA16(af[fm], bf[fn], acc[fm][fn]);
    __syncthreads();
  }
  float bs0 = bias[j0 + wc*32 + lr];
  float bs1 = bias[j0 + wc*32 + 16 + lr];
  #pragma unroll
  for (int fm=0; fm<4; fm++){
    #pragma unroll
    for (int jj=0; jj<4; jj++){
      int m = m0 + wr*64 + fm*16 + g*4 + jj;
      out[(size_t)m*384 + j0 + wc*32 + lr]      = acc[fm][0][jj] + bs0;
      out[(size_t)m*384 + j0 + wc*32 + 16 + lr] = acc[fm][1][jj] + bs1;
    }
  }
}

extern "C" void kernel_launch(void* const* d_in, const int* in_sizes, int n_in,
                              void* d_out, int out_size, void* d_ws, size_t ws_size,
                              hipStream_t stream) {
  const float* x     = (const float*)d_in[0];
  const float* vis   = (const float*)d_in[1];
  const float* wqkv  = (const float*)d_in[2];
  const float* wproj = (const float*)d_in[3];
  const float* bproj = (const float*)d_in[4];
  float* out = (float*)d_out;

  ushort* Qg  = (ushort*)d_ws;
  ushort* Kg  = Qg + SZ_;
  ushort* Vtg = Kg + SZ_;
  ushort* AO  = Vtg + SZ_;         // aliased: Xb during qkv phase, AO afterwards
  ushort* Xb  = AO;
  ushort* Wqb = AO + SZ_;
  ushort* Wpb = Wqb + 3*C_*C_;
  float*  pol_pad = (float*)(Wpb + C_*C_);

  pol_pad_k<<<(POLPAD_+255)/256, 256, 0, stream>>>(vis, pol_pad);
  cvt_all<<<2640, 256, 0, stream>>>(x, wqkv, wproj, Xb, Wqb, Wpb);
  qkv_gemm<<<dim3(98,18), 256, 0, stream>>>(Xb, Wqb, Qg, Kg, Vtg);
  attn_fwd<<<dim3(48,25), 256, 0, stream>>>(Qg, Kg, Vtg, pol_pad, AO);
  proj_gemm<<<dim3(98,6), 256, 0, stream>>>(AO, Wpb, bproj, out);
}

// Round 7
// 253.559 us; speedup vs baseline: 1.2431x; 1.2431x over previous
//
#include <hip/hip_runtime.h>

#define B_ 8
#define N_ 1568
#define NPAD_ 1600
#define C_ 384
#define H_ 6
#define D_ 64
#define BH_ 48
#define SZ_ (B_*H_*N_*D_)
#define EPS_ 1e-6f
#define CSC_ 0.18033688011112042f  /* D^-0.5 * log2(e) */

typedef short s16x8 __attribute__((ext_vector_type(8)));
typedef short s16x4 __attribute__((ext_vector_type(4)));
typedef float f32x4 __attribute__((ext_vector_type(4)));

static __device__ __forceinline__ ushort f2bf(float f){
  union { float f; unsigned u; } v; v.f = f;
  unsigned r = v.u + 0x7fffu + ((v.u >> 16) & 1u);
  return (ushort)(r >> 16);
}
static __device__ __forceinline__ unsigned cvtpk(float lo, float hi){
  unsigned r;
  asm("v_cvt_pk_bf16_f32 %0, %1, %2" : "=v"(r) : "v"(lo), "v"(hi));
  return r;
}
#define MFMA16(a,b,c) __builtin_amdgcn_mfma_f32_16x16x32_bf16((a),(b),(c),0,0,0)

#if __has_builtin(__builtin_amdgcn_exp2f)
#define EXP2F(x) __builtin_amdgcn_exp2f(x)
#else
#define EXP2F(x) exp2f(x)
#endif

// ---------------- policy pad: per-batch stride NPAD_, zeros for n in [N_, NPAD_) ----------------
#define POLPAD_ (B_*NPAD_)
__global__ __launch_bounds__(256) void pol_pad_k(const float* __restrict__ vis, float* __restrict__ pp){
  int i = blockIdx.x*256 + threadIdx.x;
  if (i < POLPAD_){
    int b = i / NPAD_, n = i - b*NPAD_;
    pp[i] = (n < N_) ? vis[b*N_ + n] : 0.f;
  }
}

// ---------------- convert f32 -> bf16 for X, w_qkv, w_proj in one launch ----------------
#define XV8_ 602112   /* 12544*384/8 */
#define WQ8_ 55296    /* 1152*384/8 */
#define WP8_ 18432    /* 384*384/8  */
__global__ __launch_bounds__(256) void cvt_all(const float* __restrict__ X, const float* __restrict__ Wq,
                                               const float* __restrict__ Wp, ushort* __restrict__ Xb,
                                               ushort* __restrict__ Wqb, ushort* __restrict__ Wpb){
  int i = blockIdx.x*256 + threadIdx.x;
  const float* src; ushort* dst; int off;
  if (i < XV8_)            { src = X;  dst = Xb;  off = i; }
  else if (i < XV8_+WQ8_)  { src = Wq; dst = Wqb; off = i - XV8_; }
  else                     { src = Wp; dst = Wpb; off = i - XV8_ - WQ8_; }
  float4 a = ((const float4*)src)[off*2];
  float4 b = ((const float4*)src)[off*2+1];
  s16x8 r;
  r[0]=(short)f2bf(a.x); r[1]=(short)f2bf(a.y); r[2]=(short)f2bf(a.z); r[3]=(short)f2bf(a.w);
  r[4]=(short)f2bf(b.x); r[5]=(short)f2bf(b.y); r[6]=(short)f2bf(b.z); r[7]=(short)f2bf(b.w);
  *(s16x8*)&dst[off*8] = r;
}

// ---------------- QKV GEMM (bf16, LDS-staged, 128x128 tile): qkv = Xb @ Wqb^T -> Q, K, V^T ----------------
__global__ __launch_bounds__(256) void qkv_gemm(const ushort* __restrict__ Xb, const ushort* __restrict__ Wb,
                                                ushort* __restrict__ Qg, ushort* __restrict__ Kg,
                                                ushort* __restrict__ Vtg){
  __shared__ __align__(16) ushort Al[128*40];
  __shared__ __align__(16) ushort Bl[128*40];
  const int tid = threadIdx.x, lane = tid&63, w = tid>>6;
  const int g = lane>>4, lr = lane&15;
  const int wr = w>>1, wc = w&1;
  const int m0 = blockIdx.x*128, j0 = blockIdx.y*128;
  const int ar = tid>>1, ah = tid&1;
  f32x4 acc[4][4];
  #pragma unroll
  for (int i=0;i<4;i++)
    #pragma unroll
    for (int j=0;j<4;j++) acc[i][j]=(f32x4){0,0,0,0};

  for (int ks=0; ks<384; ks+=32){
    const ushort* as = Xb + (size_t)(m0+ar)*384 + ks + ah*16;
    s16x8 a0 = ((const s16x8*)as)[0];
    s16x8 a1 = ((const s16x8*)as)[1];
    const ushort* bs = Wb + (size_t)(j0+ar)*384 + ks + ah*16;
    s16x8 b0 = ((const s16x8*)bs)[0];
    s16x8 b1 = ((const s16x8*)bs)[1];
    *(s16x8*)&Al[ar*40 + ah*16]     = a0;
    *(s16x8*)&Al[ar*40 + ah*16 + 8] = a1;
    *(s16x8*)&Bl[ar*40 + ah*16]     = b0;
    *(s16x8*)&Bl[ar*40 + ah*16 + 8] = b1;
    __syncthreads();
    s16x8 af[4], bf[4];
    #pragma unroll
    for (int fm=0; fm<4; fm++) af[fm] = *(const s16x8*)&Al[(wr*64+fm*16+lr)*40 + g*8];
    #pragma unroll
    for (int fn=0; fn<4; fn++) bf[fn] = *(const s16x8*)&Bl[(wc*64+fn*16+lr)*40 + g*8];
    #pragma unroll
    for (int fm=0; fm<4; fm++)
      #pragma unroll
      for (int fn=0; fn<4; fn++)
        acc[fm][fn] = MFMA16(af[fm], bf[fn], acc[fm][fn]);
    __syncthreads();
  }
  #pragma unroll
  for (int fm=0; fm<4; fm++){
    #pragma unroll
    for (int jj=0; jj<4; jj++){
      int m = m0 + wr*64 + fm*16 + g*4 + jj;
      int bi = m / N_; int n = m - bi*N_;
      #pragma unroll
      for (int fn=0; fn<4; fn++){
        int j = j0 + wc*64 + fn*16 + lr;
        int t = j/384, jc = j - t*384;
        int h = jc>>6, d = jc&63;
        float v = acc[fm][fn][jj];
        if (t==0)      Qg[((size_t)(bi*H_+h)*N_ + n)*64 + d] = f2bf(v * CSC_);
        else if (t==1) Kg[((size_t)(bi*H_+h)*N_ + n)*64 + d] = f2bf(v);
        else           Vtg[((size_t)(bi*H_+h)*64 + d)*N_ + n] = f2bf(v);
      }
    }
  }
}

// ---------------- fused flash attention: no LDS/barriers, 32 q-rows/wave, K prefetched 1 tile ahead ----------------
#define LOADK(D0,D1,TT) do{ \
  _Pragma("unroll") \
  for (int kg=0;kg<4;kg++){ \
    int kr = (TT)+kg*16+lr; kr = kr<N_?kr:N_-1; \
    const ushort* kp = Kbh + (size_t)kr*64; \
    D0[kg] = *(const s16x8*)(kp + g*8); \
    D1[kg] = *(const s16x8*)(kp + 32 + g*8); } }while(0)

#define LOADV(TT) do{ \
  _Pragma("unroll") \
  for (int fd=0;fd<4;fd++){ \
    const ushort* vp = Vbh + (size_t)(fd*16+lr)*N_ + (TT); \
    va0_[fd] = *(const s16x8*)(vp + g*8); \
    va1_[fd] = *(const s16x8*)(vp + 32 + g*8); } }while(0)

#define LOADP(TT) do{ \
  _Pragma("unroll") \
  for (int kg=0;kg<4;kg++) pmv[kg] = *(const float4*)&polp[(TT) + kg*16 + 4*g]; }while(0)

#define PROC(KC0,KC1,QF0,QF1,OO,MM,LL,QQ,DG,T0) do{ \
  f32x4 st[4]; \
  _Pragma("unroll") \
  for (int kg=0;kg<4;kg++){ f32x4 z=(f32x4){0,0,0,0}; z=MFMA16(KC0[kg],QF0,z); st[kg]=MFMA16(KC1[kg],QF1,z); } \
  float pmax; { \
    float x0=fmaxf(fmaxf(st[0][0],st[0][1]),fmaxf(st[0][2],st[0][3])); \
    float x1=fmaxf(fmaxf(st[1][0],st[1][1]),fmaxf(st[1][2],st[1][3])); \
    float x2=fmaxf(fmaxf(st[2][0],st[2][1]),fmaxf(st[2][2],st[2][3])); \
    float x3=fmaxf(fmaxf(st[3][0],st[3][1]),fmaxf(st[3][2],st[3][3])); \
    pmax=fmaxf(fmaxf(x0,x1),fmaxf(x2,x3)); \
    pmax=fmaxf(pmax,__shfl_xor(pmax,16)); pmax=fmaxf(pmax,__shfl_xor(pmax,32)); } \
  if (__any(pmax > (MM)+8.f)){ \
    float Mn=fmaxf((MM),pmax); float corr=EXP2F((MM)-Mn); (LL)*=corr; \
    _Pragma("unroll") for (int fd=0;fd<4;fd++){ OO[fd][0]*=corr;OO[fd][1]*=corr;OO[fd][2]*=corr;OO[fd][3]*=corr; } \
    (MM)=Mn; } \
  _Pragma("unroll") \
  for (int kg=0;kg<4;kg++){ \
    _Pragma("unroll") \
    for (int jj=0;jj<4;jj++){ \
      float e=EXP2F(st[kg][jj]-(MM)); float em=e*((&pmv[kg].x)[jj]); \
      int key=(T0)+kg*16+4*g+jj; \
      st[kg][jj]=((DG)&&key==(QQ))?e:em; } } \
  { float se=(st[0][0]+st[0][1])+(st[0][2]+st[0][3]); \
    se+=(st[1][0]+st[1][1])+(st[1][2]+st[1][3]); \
    se+=(st[2][0]+st[2][1])+(st[2][2]+st[2][3]); \
    se+=(st[3][0]+st[3][1])+(st[3][2]+st[3][3]); \
    se+=__shfl_xor(se,16); se+=__shfl_xor(se,32); (LL)+=se; } \
  unsigned pk[4][2]; \
  _Pragma("unroll") \
  for (int kg=0;kg<4;kg++){ pk[kg][0]=cvtpk(st[kg][0],st[kg][1]); pk[kg][1]=cvtpk(st[kg][2],st[kg][3]); } \
  union { unsigned u[4]; s16x8 v; } bfr[2]; \
  _Pragma("unroll") \
  for (int kh=0;kh<2;kh++){ \
    _Pragma("unroll") \
    for (int wd=0;wd<4;wd++){ \
      int srcl=(wd<2)?sl0:sl1; \
      unsigned q0_=(unsigned)__shfl((int)pk[2*kh][wd&1],srcl); \
      unsigned q1_=(unsigned)__shfl((int)pk[2*kh+1][wd&1],srcl); \
      bfr[kh].u[wd]=(g<2)?q0_:q1_; } } \
  _Pragma("unroll") \
  for (int fd=0;fd<4;fd++){ OO[fd]=MFMA16(va0_[fd],bfr[0].v,OO[fd]); OO[fd]=MFMA16(va1_[fd],bfr[1].v,OO[fd]); } \
}while(0)

__global__ __launch_bounds__(256,2) void attn_fwd(const ushort* __restrict__ Qg, const ushort* __restrict__ Kg,
                                                  const ushort* __restrict__ Vt, const float* __restrict__ pol,
                                                  ushort* __restrict__ AO){
  const int tid = threadIdx.x, lane = tid&63, w = tid>>6;
  const int g = lane>>4, lr = lane&15;
  const int bh = blockIdx.x; const int b = bh / H_, h = bh - b*H_;
  const int qbase = blockIdx.y*128 + w*32;
  const int qA = qbase + lr, qB = qbase + 16 + lr;
  const int qAc = qA < N_ ? qA : N_-1;
  const int qBc = qB < N_ ? qB : N_-1;
  const ushort* QrA = Qg + ((size_t)bh*N_ + qAc)*64;
  const ushort* QrB = Qg + ((size_t)bh*N_ + qBc)*64;
  const s16x8 qa0 = *(const s16x8*)(QrA + g*8);
  const s16x8 qa1 = *(const s16x8*)(QrA + 32 + g*8);
  const s16x8 qb0 = *(const s16x8*)(QrB + g*8);
  const s16x8 qb1 = *(const s16x8*)(QrB + 32 + g*8);
  const float* polp = pol + b*NPAD_;
  const ushort* Kbh = Kg + (size_t)bh*N_*64;
  const ushort* Vbh = Vt + (size_t)bh*64*N_;
  const int sl0 = ((lane>>4)&1)<<5 | lr;
  const int sl1 = sl0 + 16;
  const int dbase = qbase & ~63;   // both 16-row halves live in the same 64-aligned block

  f32x4 oA[4], oB[4];
  #pragma unroll
  for (int i=0;i<4;i++){ oA[i]=(f32x4){0,0,0,0}; oB[i]=(f32x4){0,0,0,0}; }
  float MA=-INFINITY, LA=0.f, MB=-INFINITY, LB=0.f;

  s16x8 ka0[4], ka1[4], kb0[4], kb1[4], va0_[4], va1_[4];
  float4 pmv[4];

  LOADK(ka0, ka1, 0);
  #pragma unroll 1
  for (int it=0; it<12; it++){
    const int t0 = it*128;
    LOADV(t0); LOADP(t0);
    LOADK(kb0, kb1, t0+64);                 // prefetch next tile
    PROC(ka0,ka1, qa0,qa1, oA,MA,LA,qA, (dbase==t0), t0);
    PROC(ka0,ka1, qb0,qb1, oB,MB,LB,qB, (dbase==t0), t0);
    const int t1 = t0+64;
    LOADV(t1); LOADP(t1);
    LOADK(ka0, ka1, t1+64);                 // prefetch next-next (<=1536, rows clamp)
    PROC(kb0,kb1, qa0,qa1, oA,MA,LA,qA, (dbase==t1), t1);
    PROC(kb0,kb1, qb0,qb1, oB,MB,LB,qB, (dbase==t1), t1);
  }
  { // tail tile t=1536 (prefetched into ka)
    const int t0 = 1536;
    LOADV(t0); LOADP(t0);
    PROC(ka0,ka1, qa0,qa1, oA,MA,LA,qA, (dbase==t0), t0);
    PROC(ka0,ka1, qb0,qb1, oB,MB,LB,qB, (dbase==t0), t0);
  }

  if (qA < N_){
    float inv = 1.f / (LA + EPS_);
    ushort* aop = AO + ((size_t)b*N_ + qA)*C_ + h*64 + 4*g;
    #pragma unroll
    for (int fd=0; fd<4; fd++){
      s16x4 r;
      r[0]=(short)f2bf(oA[fd][0]*inv); r[1]=(short)f2bf(oA[fd][1]*inv);
      r[2]=(short)f2bf(oA[fd][2]*inv); r[3]=(short)f2bf(oA[fd][3]*inv);
      *(s16x4*)(aop + fd*16) = r;
    }
  }
  if (qB < N_){
    float inv = 1.f / (LB + EPS_);
    ushort* aop = AO + ((size_t)b*N_ + qB)*C_ + h*64 + 4*g;
    #pragma unroll
    for (int fd=0; fd<4; fd++){
      s16x4 r;
      r[0]=(short)f2bf(oB[fd][0]*inv); r[1]=(short)f2bf(oB[fd][1]*inv);
      r[2]=(short)f2bf(oB[fd][2]*inv); r[3]=(short)f2bf(oB[fd][3]*inv);
      *(s16x4*)(aop + fd*16) = r;
    }
  }
}

// ---------------- proj GEMM (bf16, LDS-staged, 128x128 tile): out = AO @ Wpb^T + b, f32 out ----------------
__global__ __launch_bounds__(256) void proj_gemm(const ushort* __restrict__ A, const ushort* __restrict__ Wb,
                                                 const float* __restrict__ bias, float* __restrict__ out){
  __shared__ __align__(16) ushort Al[128*40];
  __shared__ __align__(16) ushort Bl[128*40];
  const int tid = threadIdx.x, lane = tid&63, w = tid>>6;
  const int g = lane>>4, lr = lane&15;
  const int wr = w>>1, wc = w&1;
  const int m0 = blockIdx.x*128, j0 = blockIdx.y*128;
  const int ar = tid>>1, ah = tid&1;
  f32x4 acc[4][4];
  #pragma unroll
  for (int i=0;i<4;i++)
    #pragma unroll
    for (int j=0;j<4;j++) acc[i][j]=(f32x4){0,0,0,0};

  for (int ks=0; ks<384; ks+=32){
    const ushort* as = A + (size_t)(m0+ar)*384 + ks + ah*16;
    s16x8 a0 = ((const s16x8*)as)[0];
    s16x8 a1 = ((const s16x8*)as)[1];
    const ushort* bs = Wb + (size_t)(j0+ar)*384 + ks + ah*16;
    s16x8 b0 = ((const s16x8*)bs)[0];
    s16x8 b1 = ((const s16x8*)bs)[1];
    *(s16x8*)&Al[ar*40 + ah*16]     = a0;
    *(s16x8*)&Al[ar*40 + ah*16 + 8] = a1;
    *(s16x8*)&Bl[ar*40 + ah*16]     = b0;
    *(s16x8*)&Bl[ar*40 + ah*16 + 8] = b1;
    __syncthreads();
    s16x8 af[4], bf[4];
    #pragma unroll
    for (int fm=0; fm<4; fm++) af[fm] = *(const s16x8*)&Al[(wr*64+fm*16+lr)*40 + g*8];
    #pragma unroll
    for (int fn=0; fn<4; fn++) bf[fn] = *(const s16x8*)&Bl[(wc*64+fn*16+lr)*40 + g*8];
    #pragma unroll
    for (int fm=0; fm<4; fm++)
      #pragma unroll
      for (int fn=0; fn<4; fn++)
        acc[fm][fn] = MFMA16(af[fm], bf[fn], acc[fm][fn]);
    __syncthreads();
  }
  float bsv[4];
  #pragma unroll
  for (int fn=0; fn<4; fn++) bsv[fn] = bias[j0 + wc*64 + fn*16 + lr];
  #pragma unroll
  for (int fm=0; fm<4; fm++){
    #pragma unroll
    for (int jj=0; jj<4; jj++){
      int m = m0 + wr*64 + fm*16 + g*4 + jj;
      #pragma unroll
      for (int fn=0; fn<4; fn++){
        int j = j0 + wc*64 + fn*16 + lr;
        out[(size_t)m*384 + j] = acc[fm][fn][jj] + bsv[fn];
      }
    }
  }
}

extern "C" void kernel_launch(void* const* d_in, const int* in_sizes, int n_in,
                              void* d_out, int out_size, void* d_ws, size_t ws_size,
                              hipStream_t stream) {
  const float* x     = (const float*)d_in[0];
  const float* vis   = (const float*)d_in[1];
  const float* wqkv  = (const float*)d_in[2];
  const float* wproj = (const float*)d_in[3];
  const float* bproj = (const float*)d_in[4];
  float* out = (float*)d_out;

  ushort* Qg  = (ushort*)d_ws;
  ushort* Kg  = Qg + SZ_;
  ushort* Vtg = Kg + SZ_;
  ushort* AO  = Vtg + SZ_;         // aliased: Xb during qkv phase, AO afterwards
  ushort* Xb  = AO;
  ushort* Wqb = AO + SZ_;
  ushort* Wpb = Wqb + 3*C_*C_;
  float*  pol_pad = (float*)(Wpb + C_*C_);

  pol_pad_k<<<(POLPAD_+255)/256, 256, 0, stream>>>(vis, pol_pad);
  cvt_all<<<2640, 256, 0, stream>>>(x, wqkv, wproj, Xb, Wqb, Wpb);
  qkv_gemm<<<dim3(98,9), 256, 0, stream>>>(Xb, Wqb, Qg, Kg, Vtg);
  attn_fwd<<<dim3(48,13), 256, 0, stream>>>(Qg, Kg, Vtg, pol_pad, AO);
  proj_gemm<<<dim3(98,3), 256, 0, stream>>>(AO, Wpb, bproj, out);
}

// Round 10
// 252.224 us; speedup vs baseline: 1.2497x; 1.0053x over previous
//
#include <hip/hip_runtime.h>

#define B_ 8
#define N_ 1568
#define NPAD_ 1600
#define C_ 384
#define H_ 6
#define D_ 64
#define BH_ 48
#define SZ_ (B_*H_*N_*D_)
#define EPS_ 1e-6f
#define CSC_ 0.18033688011112042f  /* D^-0.5 * log2(e) */

typedef short s16x8 __attribute__((ext_vector_type(8)));
typedef short s16x4 __attribute__((ext_vector_type(4)));
typedef float f32x4 __attribute__((ext_vector_type(4)));

static __device__ __forceinline__ ushort f2bf(float f){
  union { float f; unsigned u; } v; v.f = f;
  unsigned r = v.u + 0x7fffu + ((v.u >> 16) & 1u);
  return (ushort)(r >> 16);
}
static __device__ __forceinline__ unsigned cvtpk(float lo, float hi){
  unsigned r;
  asm("v_cvt_pk_bf16_f32 %0, %1, %2" : "=v"(r) : "v"(lo), "v"(hi));
  return r;
}
#define MFMA16(a,b,c) __builtin_amdgcn_mfma_f32_16x16x32_bf16((a),(b),(c),0,0,0)

#if __has_builtin(__builtin_amdgcn_exp2f)
#define EXP2F(x) __builtin_amdgcn_exp2f(x)
#else
#define EXP2F(x) exp2f(x)
#endif

// ---------------- policy pad: per-batch stride NPAD_, zeros for n in [N_, NPAD_) ----------------
#define POLPAD_ (B_*NPAD_)
__global__ __launch_bounds__(256) void pol_pad_k(const float* __restrict__ vis, float* __restrict__ pp){
  int i = blockIdx.x*256 + threadIdx.x;
  if (i < POLPAD_){
    int b = i / NPAD_, n = i - b*NPAD_;
    pp[i] = (n < N_) ? vis[b*N_ + n] : 0.f;
  }
}

// ---------------- convert f32 -> bf16 for X, w_qkv, w_proj in one launch ----------------
#define XV8_ 602112   /* 12544*384/8 */
#define WQ8_ 55296    /* 1152*384/8 */
#define WP8_ 18432    /* 384*384/8  */
__global__ __launch_bounds__(256) void cvt_all(const float* __restrict__ X, const float* __restrict__ Wq,
                                               const float* __restrict__ Wp, ushort* __restrict__ Xb,
                                               ushort* __restrict__ Wqb, ushort* __restrict__ Wpb){
  int i = blockIdx.x*256 + threadIdx.x;
  const float* src; ushort* dst; int off;
  if (i < XV8_)            { src = X;  dst = Xb;  off = i; }
  else if (i < XV8_+WQ8_)  { src = Wq; dst = Wqb; off = i - XV8_; }
  else                     { src = Wp; dst = Wpb; off = i - XV8_ - WQ8_; }
  float4 a = ((const float4*)src)[off*2];
  float4 b = ((const float4*)src)[off*2+1];
  s16x8 r;
  r[0]=(short)f2bf(a.x); r[1]=(short)f2bf(a.y); r[2]=(short)f2bf(a.z); r[3]=(short)f2bf(a.w);
  r[4]=(short)f2bf(b.x); r[5]=(short)f2bf(b.y); r[6]=(short)f2bf(b.z); r[7]=(short)f2bf(b.w);
  *(s16x8*)&dst[off*8] = r;
}

// ---------------- QKV GEMM (bf16, LDS-staged, 128x128 tile): qkv = Xb @ Wqb^T ----------------
// vmode=1: write V row-major to Vg (coalesced; Vt produced by v_tr). vmode=0: legacy Vt scatter.
__global__ __launch_bounds__(256) void qkv_gemm(const ushort* __restrict__ Xb, const ushort* __restrict__ Wb,
                                                ushort* __restrict__ Qg, ushort* __restrict__ Kg,
                                                ushort* __restrict__ Vg, ushort* __restrict__ Vtg,
                                                int vmode){
  __shared__ __align__(16) ushort Al[128*40];
  __shared__ __align__(16) ushort Bl[128*40];
  const int tid = threadIdx.x, lane = tid&63, w = tid>>6;
  const int g = lane>>4, lr = lane&15;
  const int wr = w>>1, wc = w&1;
  const int m0 = blockIdx.x*128, j0 = blockIdx.y*128;
  const int ar = tid>>1, ah = tid&1;
  f32x4 acc[4][4];
  #pragma unroll
  for (int i=0;i<4;i++)
    #pragma unroll
    for (int j=0;j<4;j++) acc[i][j]=(f32x4){0,0,0,0};

  for (int ks=0; ks<384; ks+=32){
    const ushort* as = Xb + (size_t)(m0+ar)*384 + ks + ah*16;
    s16x8 a0 = ((const s16x8*)as)[0];
    s16x8 a1 = ((const s16x8*)as)[1];
    const ushort* bs = Wb + (size_t)(j0+ar)*384 + ks + ah*16;
    s16x8 b0 = ((const s16x8*)bs)[0];
    s16x8 b1 = ((const s16x8*)bs)[1];
    *(s16x8*)&Al[ar*40 + ah*16]     = a0;
    *(s16x8*)&Al[ar*40 + ah*16 + 8] = a1;
    *(s16x8*)&Bl[ar*40 + ah*16]     = b0;
    *(s16x8*)&Bl[ar*40 + ah*16 + 8] = b1;
    __syncthreads();
    s16x8 af[4], bf[4];
    #pragma unroll
    for (int fm=0; fm<4; fm++) af[fm] = *(const s16x8*)&Al[(wr*64+fm*16+lr)*40 + g*8];
    #pragma unroll
    for (int fn=0; fn<4; fn++) bf[fn] = *(const s16x8*)&Bl[(wc*64+fn*16+lr)*40 + g*8];
    #pragma unroll
    for (int fm=0; fm<4; fm++)
      #pragma unroll
      for (int fn=0; fn<4; fn++)
        acc[fm][fn] = MFMA16(af[fm], bf[fn], acc[fm][fn]);
    __syncthreads();
  }
  #pragma unroll
  for (int fm=0; fm<4; fm++){
    #pragma unroll
    for (int jj=0; jj<4; jj++){
      int m = m0 + wr*64 + fm*16 + g*4 + jj;
      int bi = m / N_; int n = m - bi*N_;
      #pragma unroll
      for (int fn=0; fn<4; fn++){
        int j = j0 + wc*64 + fn*16 + lr;
        int t = j/384, jc = j - t*384;
        int h = jc>>6, d = jc&63;
        float v = acc[fm][fn][jj];
        if (t==0)      Qg[((size_t)(bi*H_+h)*N_ + n)*64 + d] = f2bf(v * CSC_);
        else if (t==1) Kg[((size_t)(bi*H_+h)*N_ + n)*64 + d] = f2bf(v);
        else {
          if (vmode) Vg[((size_t)(bi*H_+h)*N_ + n)*64 + d] = f2bf(v);
          else       Vtg[((size_t)(bi*H_+h)*64 + d)*N_ + n] = f2bf(v);
        }
      }
    }
  }
}

// ---------------- V transpose: Vg[bh][n][d] -> Vt[bh][d][n], LDS-staged, coalesced both sides ----------------
__global__ __launch_bounds__(256) void v_tr(const ushort* __restrict__ Vg, ushort* __restrict__ Vt){
  __shared__ ushort lds[32*72];
  const int bh = blockIdx.x, k0 = blockIdx.y*32;
  const int tid = threadIdx.x;
  const int r = tid>>3, dc = (tid&7)*8;
  *(s16x8*)&lds[r*72 + dc] = *(const s16x8*)&Vg[((size_t)bh*N_ + k0 + r)*64 + dc];
  __syncthreads();
  const int d = tid>>2, kc = (tid&3)*8;
  s16x8 o;
  #pragma unroll
  for (int i=0;i<8;i++) o[i] = (short)lds[(kc+i)*72 + d];
  *(s16x8*)&Vt[((size_t)bh*64 + d)*N_ + k0 + kc] = o;
}

// ---------------- fused flash attention: 1-wave blocks, 32 q-rows/wave, K prefetched 1 tile ahead ----------------
#define LOADK(D0,D1,TT) do{ \
  _Pragma("unroll") \
  for (int kg=0;kg<4;kg++){ \
    int kr = (TT)+kg*16+lr; kr = kr<N_?kr:N_-1; \
    const ushort* kp = Kbh + (size_t)kr*64; \
    D0[kg] = *(const s16x8*)(kp + g*8); \
    D1[kg] = *(const s16x8*)(kp + 32 + g*8); } }while(0)

#define LOADV(TT) do{ \
  _Pragma("unroll") \
  for (int fd=0;fd<4;fd++){ \
    const ushort* vp = Vbh + (size_t)(fd*16+lr)*N_ + (TT); \
    va0_[fd] = *(const s16x8*)(vp + g*8); \
    va1_[fd] = *(const s16x8*)(vp + 32 + g*8); } }while(0)

#define LOADP(TT) do{ \
  _Pragma("unroll") \
  for (int kg=0;kg<4;kg++) pmv[kg] = *(const float4*)&polp[(TT) + kg*16 + 4*g]; }while(0)

#define PROC(KC0,KC1,QF0,QF1,OO,MM,LL,QQ,DG,T0) do{ \
  f32x4 st[4]; \
  __builtin_amdgcn_s_setprio(1); \
  _Pragma("unroll") \
  for (int kg=0;kg<4;kg++){ f32x4 z=(f32x4){0,0,0,0}; z=MFMA16(KC0[kg],QF0,z); st[kg]=MFMA16(KC1[kg],QF1,z); } \
  __builtin_amdgcn_s_setprio(0); \
  float pmax; { \
    float x0=fmaxf(fmaxf(st[0][0],st[0][1]),fmaxf(st[0][2],st[0][3])); \
    float x1=fmaxf(fmaxf(st[1][0],st[1][1]),fmaxf(st[1][2],st[1][3])); \
    float x2=fmaxf(fmaxf(st[2][0],st[2][1]),fmaxf(st[2][2],st[2][3])); \
    float x3=fmaxf(fmaxf(st[3][0],st[3][1]),fmaxf(st[3][2],st[3][3])); \
    pmax=fmaxf(fmaxf(x0,x1),fmaxf(x2,x3)); \
    pmax=fmaxf(pmax,__shfl_xor(pmax,16)); pmax=fmaxf(pmax,__shfl_xor(pmax,32)); } \
  if (__any(pmax > (MM)+8.f)){ \
    float Mn=fmaxf((MM),pmax); float corr=EXP2F((MM)-Mn); (LL)*=corr; \
    _Pragma("unroll") for (int fd=0;fd<4;fd++){ OO[fd][0]*=corr;OO[fd][1]*=corr;OO[fd][2]*=corr;OO[fd][3]*=corr; } \
    (MM)=Mn; } \
  _Pragma("unroll") \
  for (int kg=0;kg<4;kg++){ \
    _Pragma("unroll") \
    for (int jj=0;jj<4;jj++){ \
      float e=EXP2F(st[kg][jj]-(MM)); float em=e*((&pmv[kg].x)[jj]); \
      int key=(T0)+kg*16+4*g+jj; \
      st[kg][jj]=((DG)&&key==(QQ))?e:em; } } \
  { float se=(st[0][0]+st[0][1])+(st[0][2]+st[0][3]); \
    se+=(st[1][0]+st[1][1])+(st[1][2]+st[1][3]); \
    se+=(st[2][0]+st[2][1])+(st[2][2]+st[2][3]); \
    se+=(st[3][0]+st[3][1])+(st[3][2]+st[3][3]); \
    se+=__shfl_xor(se,16); se+=__shfl_xor(se,32); (LL)+=se; } \
  unsigned pk[4][2]; \
  _Pragma("unroll") \
  for (int kg=0;kg<4;kg++){ pk[kg][0]=cvtpk(st[kg][0],st[kg][1]); pk[kg][1]=cvtpk(st[kg][2],st[kg][3]); } \
  union { unsigned u[4]; s16x8 v; } bfr[2]; \
  _Pragma("unroll") \
  for (int kh=0;kh<2;kh++){ \
    _Pragma("unroll") \
    for (int wd=0;wd<4;wd++){ \
      int srcl=(wd<2)?sl0:sl1; \
      unsigned q0_=(unsigned)__shfl((int)pk[2*kh][wd&1],srcl); \
      unsigned q1_=(unsigned)__shfl((int)pk[2*kh+1][wd&1],srcl); \
      bfr[kh].u[wd]=(g<2)?q0_:q1_; } } \
  __builtin_amdgcn_s_setprio(1); \
  _Pragma("unroll") \
  for (int fd=0;fd<4;fd++){ OO[fd]=MFMA16(va0_[fd],bfr[0].v,OO[fd]); OO[fd]=MFMA16(va1_[fd],bfr[1].v,OO[fd]); } \
  __builtin_amdgcn_s_setprio(0); \
}while(0)

__global__ __launch_bounds__(64,2) void attn_fwd(const ushort* __restrict__ Qg, const ushort* __restrict__ Kg,
                                                 const ushort* __restrict__ Vt, const float* __restrict__ pol,
                                                 ushort* __restrict__ AO){
  const int lane = threadIdx.x & 63;
  const int g = lane>>4, lr = lane&15;
  const int bh = blockIdx.x; const int b = bh / H_, h = bh - b*H_;
  const int qbase = blockIdx.y*32;
  const int qA = qbase + lr, qB = qbase + 16 + lr;
  const ushort* QrA = Qg + ((size_t)bh*N_ + qA)*64;
  const ushort* QrB = Qg + ((size_t)bh*N_ + qB)*64;
  const s16x8 qa0 = *(const s16x8*)(QrA + g*8);
  const s16x8 qa1 = *(const s16x8*)(QrA + 32 + g*8);
  const s16x8 qb0 = *(const s16x8*)(QrB + g*8);
  const s16x8 qb1 = *(const s16x8*)(QrB + 32 + g*8);
  const float* polp = pol + b*NPAD_;
  const ushort* Kbh = Kg + (size_t)bh*N_*64;
  const ushort* Vbh = Vt + (size_t)bh*64*N_;
  const int sl0 = ((lane>>4)&1)<<5 | lr;
  const int sl1 = sl0 + 16;
  const int dbase = qbase & ~63;   // 32-row block lies in one 64-aligned key tile

  f32x4 oA[4], oB[4];
  #pragma unroll
  for (int i=0;i<4;i++){ oA[i]=(f32x4){0,0,0,0}; oB[i]=(f32x4){0,0,0,0}; }
  float MA=-INFINITY, LA=0.f, MB=-INFINITY, LB=0.f;

  s16x8 ka0[4], ka1[4], kb0[4], kb1[4], va0_[4], va1_[4];
  float4 pmv[4];

  LOADK(ka0, ka1, 0);
  #pragma unroll 1
  for (int it=0; it<12; it++){
    const int t0 = it*128;
    LOADV(t0); LOADP(t0);
    LOADK(kb0, kb1, t0+64);                 // prefetch next tile
    __builtin_amdgcn_sched_barrier(0);      // pin prefetch issue point
    PROC(ka0,ka1, qa0,qa1, oA,MA,LA,qA, (dbase==t0), t0);
    PROC(ka0,ka1, qb0,qb1, oB,MB,LB,qB, (dbase==t0), t0);
    const int t1 = t0+64;
    LOADV(t1); LOADP(t1);
    LOADK(ka0, ka1, t1+64);                 // prefetch next-next (rows clamp at tail)
    __builtin_amdgcn_sched_barrier(0);
    PROC(kb0,kb1, qa0,qa1, oA,MA,LA,qA, (dbase==t1), t1);
    PROC(kb0,kb1, qb0,qb1, oB,MB,LB,qB, (dbase==t1), t1);
  }
  { // tail tile t=1536 (prefetched into ka)
    const int t0 = 1536;
    LOADV(t0); LOADP(t0);
    PROC(ka0,ka1, qa0,qa1, oA,MA,LA,qA, (dbase==t0), t0);
    PROC(ka0,ka1, qb0,qb1, oB,MB,LB,qB, (dbase==t0), t0);
  }

  {
    float inv = 1.f / (LA + EPS_);
    ushort* aop = AO + ((size_t)b*N_ + qA)*C_ + h*64 + 4*g;
    #pragma unroll
    for (int fd=0; fd<4; fd++){
      s16x4 r;
      r[0]=(short)f2bf(oA[fd][0]*inv); r[1]=(short)f2bf(oA[fd][1]*inv);
      r[2]=(short)f2bf(oA[fd][2]*inv); r[3]=(short)f2bf(oA[fd][3]*inv);
      *(s16x4*)(aop + fd*16) = r;
    }
  }
  {
    float inv = 1.f / (LB + EPS_);
    ushort* aop = AO + ((size_t)b*N_ + qB)*C_ + h*64 + 4*g;
    #pragma unroll
    for (int fd=0; fd<4; fd++){
      s16x4 r;
      r[0]=(short)f2bf(oB[fd][0]*inv); r[1]=(short)f2bf(oB[fd][1]*inv);
      r[2]=(short)f2bf(oB[fd][2]*inv); r[3]=(short)f2bf(oB[fd][3]*inv);
      *(s16x4*)(aop + fd*16) = r;
    }
  }
}

// ---------------- proj GEMM (bf16, LDS-staged, 128x128 tile): out = AO @ Wpb^T + b, f32 out ----------------
__global__ __launch_bounds__(256) void proj_gemm(const ushort* __restrict__ A, const ushort* __restrict__ Wb,
                                                 const float* __restrict__ bias, float* __restrict__ out){
  __shared__ __align__(16) ushort Al[128*40];
  __shared__ __align__(16) ushort Bl[128*40];
  const int tid = threadIdx.x, lane = tid&63, w = tid>>6;
  const int g = lane>>4, lr = lane&15;
  const int wr = w>>1, wc = w&1;
  const int m0 = blockIdx.x*128, j0 = blockIdx.y*128;
  const int ar = tid>>1, ah = tid&1;
  f32x4 acc[4][4];
  #pragma unroll
  for (int i=0;i<4;i++)
    #pragma unroll
    for (int j=0;j<4;j++) acc[i][j]=(f32x4){0,0,0,0};

  for (int ks=0; ks<384; ks+=32){
    const ushort* as = A + (size_t)(m0+ar)*384 + ks + ah*16;
    s16x8 a0 = ((const s16x8*)as)[0];
    s16x8 a1 = ((const s16x8*)as)[1];
    const ushort* bs = Wb + (size_t)(j0+ar)*384 + ks + ah*16;
    s16x8 b0 = ((const s16x8*)bs)[0];
    s16x8 b1 = ((const s16x8*)bs)[1];
    *(s16x8*)&Al[ar*40 + ah*16]     = a0;
    *(s16x8*)&Al[ar*40 + ah*16 + 8] = a1;
    *(s16x8*)&Bl[ar*40 + ah*16]     = b0;
    *(s16x8*)&Bl[ar*40 + ah*16 + 8] = b1;
    __syncthreads();
    s16x8 af[4], bf[4];
    #pragma unroll
    for (int fm=0; fm<4; fm++) af[fm] = *(const s16x8*)&Al[(wr*64+fm*16+lr)*40 + g*8];
    #pragma unroll
    for (int fn=0; fn<4; fn++) bf[fn] = *(const s16x8*)&Bl[(wc*64+fn*16+lr)*40 + g*8];
    #pragma unroll
    for (int fm=0; fm<4; fm++)
      #pragma unroll
      for (int fn=0; fn<4; fn++)
        acc[fm][fn] = MFMA16(af[fm], bf[fn], acc[fm][fn]);
    __syncthreads();
  }
  float bsv[4];
  #pragma unroll
  for (int fn=0; fn<4; fn++) bsv[fn] = bias[j0 + wc*64 + fn*16 + lr];
  #pragma unroll
  for (int fm=0; fm<4; fm++){
    #pragma unroll
    for (int jj=0; jj<4; jj++){
      int m = m0 + wr*64 + fm*16 + g*4 + jj;
      #pragma unroll
      for (int fn=0; fn<4; fn++){
        int j = j0 + wc*64 + fn*16 + lr;
        out[(size_t)m*384 + j] = acc[fm][fn][jj] + bsv[fn];
      }
    }
  }
}

extern "C" void kernel_launch(void* const* d_in, const int* in_sizes, int n_in,
                              void* d_out, int out_size, void* d_ws, size_t ws_size,
                              hipStream_t stream) {
  const float* x     = (const float*)d_in[0];
  const float* vis   = (const float*)d_in[1];
  const float* wqkv  = (const float*)d_in[2];
  const float* wproj = (const float*)d_in[3];
  const float* bproj = (const float*)d_in[4];
  float* out = (float*)d_out;

  // Layout (tr path): Qg | Kg | Vtg | AO/Xb | Vg | Wqb | Wpb | pol
  ushort* Qg  = (ushort*)d_ws;
  ushort* Kg  = Qg + SZ_;
  ushort* Vtg = Kg + SZ_;
  ushort* AO  = Vtg + SZ_;         // aliased: Xb during qkv phase, AO afterwards
  ushort* Xb  = AO;
  ushort* Vg  = AO + SZ_;          // 5th buffer (only used on tr path)
  size_t need_tr = (size_t)5*SZ_*2 + (size_t)(3*C_*C_ + C_*C_)*2 + (size_t)POLPAD_*4;
  int tr = (ws_size >= need_tr) ? 1 : 0;
  ushort* Wqb = tr ? (Vg + SZ_) : (Vg);          // without tr, Vg slot unused -> weights move up
  ushort* Wpb = Wqb + 3*C_*C_;
  float*  pol_pad = (float*)(Wpb + C_*C_);

  pol_pad_k<<<(POLPAD_+255)/256, 256, 0, stream>>>(vis, pol_pad);
  cvt_all<<<2640, 256, 0, stream>>>(x, wqkv, wproj, Xb, Wqb, Wpb);
  qkv_gemm<<<dim3(98,9), 256, 0, stream>>>(Xb, Wqb, Qg, Kg, Vg, Vtg, tr);
  if (tr) v_tr<<<dim3(48,49), 256, 0, stream>>>(Vg, Vtg);
  attn_fwd<<<dim3(48,49), 64, 0, stream>>>(Qg, Kg, Vtg, pol_pad, AO);
  proj_gemm<<<dim3(98,3), 256, 0, stream>>>(AO, Wpb, bproj, out);
}

// Round 11
// 222.294 us; speedup vs baseline: 1.4180x; 1.1346x over previous
//
#include <hip/hip_runtime.h>

#define B_ 8
#define N_ 1568
#define NPAD_ 1600
#define C_ 384
#define H_ 6
#define D_ 64
#define BH_ 48
#define SZ_ (B_*H_*N_*D_)
#define EPS_ 1e-6f
#define CSC_ 0.18033688011112042f  /* D^-0.5 * log2(e) */

typedef short s16x8 __attribute__((ext_vector_type(8)));
typedef short s16x4 __attribute__((ext_vector_type(4)));
typedef float f32x4 __attribute__((ext_vector_type(4)));

static __device__ __forceinline__ ushort f2bf(float f){
  union { float f; unsigned u; } v; v.f = f;
  unsigned r = v.u + 0x7fffu + ((v.u >> 16) & 1u);
  return (ushort)(r >> 16);
}
static __device__ __forceinline__ unsigned cvtpk(float lo, float hi){
  unsigned r;
  asm("v_cvt_pk_bf16_f32 %0, %1, %2" : "=v"(r) : "v"(lo), "v"(hi));
  return r;
}
#define MFMA16(a,b,c) __builtin_amdgcn_mfma_f32_16x16x32_bf16((a),(b),(c),0,0,0)

#if __has_builtin(__builtin_amdgcn_exp2f)
#define EXP2F(x) __builtin_amdgcn_exp2f(x)
#else
#define EXP2F(x) exp2f(x)
#endif

// ---------------- convert f32 -> bf16 for X, w_qkv, w_proj + policy pad, one launch ----------------
#define XV8_ 602112   /* 12544*384/8 */
#define WQ8_ 55296    /* 1152*384/8 */
#define WP8_ 18432    /* 384*384/8  */
#define TOT8_ (XV8_+WQ8_+WP8_)
#define POLPAD_ (B_*NPAD_)
__global__ __launch_bounds__(256) void cvt_pol(const float* __restrict__ X, const float* __restrict__ Wq,
                                               const float* __restrict__ Wp, const float* __restrict__ vis,
                                               ushort* __restrict__ Xb, ushort* __restrict__ Wqb,
                                               ushort* __restrict__ Wpb, float* __restrict__ pp){
  int i = blockIdx.x*256 + threadIdx.x;
  if (i < TOT8_){
    const float* src; ushort* dst; int off;
    if (i < XV8_)            { src = X;  dst = Xb;  off = i; }
    else if (i < XV8_+WQ8_)  { src = Wq; dst = Wqb; off = i - XV8_; }
    else                     { src = Wp; dst = Wpb; off = i - XV8_ - WQ8_; }
    float4 a = ((const float4*)src)[off*2];
    float4 b = ((const float4*)src)[off*2+1];
    s16x8 r;
    r[0]=(short)f2bf(a.x); r[1]=(short)f2bf(a.y); r[2]=(short)f2bf(a.z); r[3]=(short)f2bf(a.w);
    r[4]=(short)f2bf(b.x); r[5]=(short)f2bf(b.y); r[6]=(short)f2bf(b.z); r[7]=(short)f2bf(b.w);
    *(s16x8*)&dst[off*8] = r;
  } else {
    int p = i - TOT8_;
    if (p < POLPAD_){
      int b = p / NPAD_, n = p - b*NPAD_;
      pp[p] = (n < N_) ? vis[b*N_ + n] : 0.f;
    }
  }
}

// ---------------- QKV GEMM (bf16, LDS-staged, 128x128 tile): qkv = Xb @ Wqb^T ----------------
// vmode=1: write V row-major to Vg (coalesced; Vt produced by v_tr). vmode=0: legacy Vt scatter.
__global__ __launch_bounds__(256) void qkv_gemm(const ushort* __restrict__ Xb, const ushort* __restrict__ Wb,
                                                ushort* __restrict__ Qg, ushort* __restrict__ Kg,
                                                ushort* __restrict__ Vg, ushort* __restrict__ Vtg,
                                                int vmode){
  __shared__ __align__(16) ushort Al[128*40];
  __shared__ __align__(16) ushort Bl[128*40];
  const int tid = threadIdx.x, lane = tid&63, w = tid>>6;
  const int g = lane>>4, lr = lane&15;
  const int wr = w>>1, wc = w&1;
  const int m0 = blockIdx.x*128, j0 = blockIdx.y*128;
  const int ar = tid>>1, ah = tid&1;
  f32x4 acc[4][4];
  #pragma unroll
  for (int i=0;i<4;i++)
    #pragma unroll
    for (int j=0;j<4;j++) acc[i][j]=(f32x4){0,0,0,0};

  for (int ks=0; ks<384; ks+=32){
    const ushort* as = Xb + (size_t)(m0+ar)*384 + ks + ah*16;
    s16x8 a0 = ((const s16x8*)as)[0];
    s16x8 a1 = ((const s16x8*)as)[1];
    const ushort* bs = Wb + (size_t)(j0+ar)*384 + ks + ah*16;
    s16x8 b0 = ((const s16x8*)bs)[0];
    s16x8 b1 = ((const s16x8*)bs)[1];
    *(s16x8*)&Al[ar*40 + ah*16]     = a0;
    *(s16x8*)&Al[ar*40 + ah*16 + 8] = a1;
    *(s16x8*)&Bl[ar*40 + ah*16]     = b0;
    *(s16x8*)&Bl[ar*40 + ah*16 + 8] = b1;
    __syncthreads();
    s16x8 af[4], bf[4];
    #pragma unroll
    for (int fm=0; fm<4; fm++) af[fm] = *(const s16x8*)&Al[(wr*64+fm*16+lr)*40 + g*8];
    #pragma unroll
    for (int fn=0; fn<4; fn++) bf[fn] = *(const s16x8*)&Bl[(wc*64+fn*16+lr)*40 + g*8];
    #pragma unroll
    for (int fm=0; fm<4; fm++)
      #pragma unroll
      for (int fn=0; fn<4; fn++)
        acc[fm][fn] = MFMA16(af[fm], bf[fn], acc[fm][fn]);
    __syncthreads();
  }
  #pragma unroll
  for (int fm=0; fm<4; fm++){
    #pragma unroll
    for (int jj=0; jj<4; jj++){
      int m = m0 + wr*64 + fm*16 + g*4 + jj;
      int bi = m / N_; int n = m - bi*N_;
      #pragma unroll
      for (int fn=0; fn<4; fn++){
        int j = j0 + wc*64 + fn*16 + lr;
        int t = j/384, jc = j - t*384;
        int h = jc>>6, d = jc&63;
        float v = acc[fm][fn][jj];
        if (t==0)      Qg[((size_t)(bi*H_+h)*N_ + n)*64 + d] = f2bf(v * CSC_);
        else if (t==1) Kg[((size_t)(bi*H_+h)*N_ + n)*64 + d] = f2bf(v);
        else {
          if (vmode) Vg[((size_t)(bi*H_+h)*N_ + n)*64 + d] = f2bf(v);
          else       Vtg[((size_t)(bi*H_+h)*64 + d)*N_ + n] = f2bf(v);
        }
      }
    }
  }
}

// ---------------- V transpose: Vg[bh][n][d] -> Vt[bh][d][n], LDS-staged, coalesced both sides ----------------
__global__ __launch_bounds__(256) void v_tr(const ushort* __restrict__ Vg, ushort* __restrict__ Vt){
  __shared__ ushort lds[32*72];
  const int bh = blockIdx.x, k0 = blockIdx.y*32;
  const int tid = threadIdx.x;
  const int r = tid>>3, dc = (tid&7)*8;
  *(s16x8*)&lds[r*72 + dc] = *(const s16x8*)&Vg[((size_t)bh*N_ + k0 + r)*64 + dc];
  __syncthreads();
  const int d = tid>>2, kc = (tid&3)*8;
  s16x8 o;
  #pragma unroll
  for (int i=0;i<8;i++) o[i] = (short)lds[(kc+i)*72 + d];
  *(s16x8*)&Vt[((size_t)bh*64 + d)*N_ + k0 + kc] = o;
}

// ---------------- fused flash attention: 4-wave blocks, KVBLK=64 double-buffered padded LDS ----------------
#define LDST_ 72   /* LDS row stride (elements): 144B -> bank-perfect staging, 2-way reads */

#define LOADP(TT) do{ \
  _Pragma("unroll") \
  for (int kg=0;kg<4;kg++) pmv[kg] = *(const float4*)&polp[(TT) + kg*16 + 4*g]; }while(0)

#define STAGEISSUE(T0N) do{ \
  int kr_ = (T0N)+sr; kr_ = kr_<N_?kr_:N_-1; \
  const ushort* kp_ = Kbh + (size_t)kr_*64 + sc2*8; \
  sk0 = *(const s16x8*)(kp_); sk1 = *(const s16x8*)(kp_+8); \
  const ushort* vp_ = Vbh + (size_t)sr*N_ + (T0N) + sc2*8; \
  sv0 = *(const s16x8*)(vp_); sv1 = *(const s16x8*)(vp_+8); \
}while(0)

#define STAGEWRITE(KD,VD) do{ \
  *(s16x8*)&(KD)[sr*LDST_ + sc2*8]     = sk0; \
  *(s16x8*)&(KD)[sr*LDST_ + sc2*8 + 8] = sk1; \
  *(s16x8*)&(VD)[sr*LDST_ + sc2*8]     = sv0; \
  *(s16x8*)&(VD)[sr*LDST_ + sc2*8 + 8] = sv1; }while(0)

#define PROCQ(KB,VB,QF0,QF1,OO,MM,LL,QQ,DG,T0) do{ \
  f32x4 st[4]; \
  __builtin_amdgcn_s_setprio(1); \
  _Pragma("unroll") \
  for (int kg=0;kg<4;kg++){ \
    const ushort* krp_ = (KB) + (kg*16+lr)*LDST_ + g*8; \
    s16x8 kf0_ = *(const s16x8*)(krp_); \
    s16x8 kf1_ = *(const s16x8*)(krp_+32); \
    f32x4 z=(f32x4){0,0,0,0}; z=MFMA16(kf0_,QF0,z); st[kg]=MFMA16(kf1_,QF1,z); } \
  __builtin_amdgcn_s_setprio(0); \
  float pmax; { \
    float x0=fmaxf(fmaxf(st[0][0],st[0][1]),fmaxf(st[0][2],st[0][3])); \
    float x1=fmaxf(fmaxf(st[1][0],st[1][1]),fmaxf(st[1][2],st[1][3])); \
    float x2=fmaxf(fmaxf(st[2][0],st[2][1]),fmaxf(st[2][2],st[2][3])); \
    float x3=fmaxf(fmaxf(st[3][0],st[3][1]),fmaxf(st[3][2],st[3][3])); \
    pmax=fmaxf(fmaxf(x0,x1),fmaxf(x2,x3)); \
    pmax=fmaxf(pmax,__shfl_xor(pmax,16)); pmax=fmaxf(pmax,__shfl_xor(pmax,32)); } \
  if (__any(pmax > (MM)+8.f)){ \
    float Mn=fmaxf((MM),pmax); float corr=EXP2F((MM)-Mn); (LL)*=corr; \
    _Pragma("unroll") for (int fd=0;fd<4;fd++){ OO[fd][0]*=corr;OO[fd][1]*=corr;OO[fd][2]*=corr;OO[fd][3]*=corr; } \
    (MM)=Mn; } \
  _Pragma("unroll") \
  for (int kg=0;kg<4;kg++){ \
    _Pragma("unroll") \
    for (int jj=0;jj<4;jj++){ \
      float e=EXP2F(st[kg][jj]-(MM)); float em=e*((&pmv[kg].x)[jj]); \
      int key=(T0)+kg*16+4*g+jj; \
      st[kg][jj]=((DG)&&key==(QQ))?e:em; } } \
  { float se=(st[0][0]+st[0][1])+(st[0][2]+st[0][3]); \
    se+=(st[1][0]+st[1][1])+(st[1][2]+st[1][3]); \
    se+=(st[2][0]+st[2][1])+(st[2][2]+st[2][3]); \
    se+=(st[3][0]+st[3][1])+(st[3][2]+st[3][3]); \
    se+=__shfl_xor(se,16); se+=__shfl_xor(se,32); (LL)+=se; } \
  unsigned pk[4][2]; \
  _Pragma("unroll") \
  for (int kg=0;kg<4;kg++){ pk[kg][0]=cvtpk(st[kg][0],st[kg][1]); pk[kg][1]=cvtpk(st[kg][2],st[kg][3]); } \
  union { unsigned u[4]; s16x8 v; } bfr[2]; \
  _Pragma("unroll") \
  for (int kh=0;kh<2;kh++){ \
    _Pragma("unroll") \
    for (int wd=0;wd<4;wd++){ \
      int srcl=(wd<2)?sl0:sl1; \
      unsigned q0_=(unsigned)__shfl((int)pk[2*kh][wd&1],srcl); \
      unsigned q1_=(unsigned)__shfl((int)pk[2*kh+1][wd&1],srcl); \
      bfr[kh].u[wd]=(g<2)?q0_:q1_; } } \
  __builtin_amdgcn_s_setprio(1); \
  _Pragma("unroll") \
  for (int fd=0;fd<4;fd++){ \
    const ushort* vrp_ = (VB) + (fd*16+lr)*LDST_ + g*8; \
    s16x8 va0_ = *(const s16x8*)(vrp_); \
    s16x8 va1_ = *(const s16x8*)(vrp_+32); \
    OO[fd]=MFMA16(va0_,bfr[0].v,OO[fd]); OO[fd]=MFMA16(va1_,bfr[1].v,OO[fd]); } \
  __builtin_amdgcn_s_setprio(0); \
}while(0)

#define TILE(KB,VB,T0,STG,T0N,KD,VD) do{ \
  if (STG){ STAGEISSUE(T0N); __builtin_amdgcn_sched_barrier(0); } \
  LOADP(T0); \
  const bool dg_ = ((qA0 & ~63) == (T0)); \
  PROCQ(KB,VB, qa0,qa1, oA,MA,LA,qA, dg_, T0); \
  PROCQ(KB,VB, qb0,qb1, oB,MB,LB,qB, dg_, T0); \
  if (STG){ STAGEWRITE(KD,VD); __syncthreads(); } \
}while(0)

__global__ __launch_bounds__(256,2) void attn_fwd(const ushort* __restrict__ Qg, const ushort* __restrict__ Kg,
                                                  const ushort* __restrict__ Vt, const float* __restrict__ pol,
                                                  ushort* __restrict__ AO){
  __shared__ __align__(16) ushort Kl0[64*LDST_], Kl1[64*LDST_];
  __shared__ __align__(16) ushort Vl0[64*LDST_], Vl1[64*LDST_];
  const int tid = threadIdx.x, lane = tid&63, w = tid>>6;
  const int g = lane>>4, lr = lane&15;
  // XCD-chunked swizzle: 624 = 8 XCDs x 78; each XCD gets 6 consecutive bh's
  const int orig = blockIdx.x;
  const int wg = (orig & 7)*78 + (orig >> 3);
  const int bh = wg / 13, qb = wg - bh*13;
  const int b = bh / H_, h = bh - b*H_;
  const int qA0 = qb*128 + w*32;
  const int qA = qA0 + lr, qB = qA0 + 16 + lr;
  const int qAc = qA < N_ ? qA : N_-1;
  const int qBc = qB < N_ ? qB : N_-1;
  const ushort* QrA = Qg + ((size_t)bh*N_ + qAc)*64;
  const ushort* QrB = Qg + ((size_t)bh*N_ + qBc)*64;
  const s16x8 qa0 = *(const s16x8*)(QrA + g*8);
  const s16x8 qa1 = *(const s16x8*)(QrA + 32 + g*8);
  const s16x8 qb0 = *(const s16x8*)(QrB + g*8);
  const s16x8 qb1 = *(const s16x8*)(QrB + 32 + g*8);
  const float* polp = pol + b*NPAD_;
  const ushort* Kbh = Kg + (size_t)bh*N_*64;
  const ushort* Vbh = Vt + (size_t)bh*64*N_;
  const int sl0 = ((lane>>4)&1)<<5 | lr;
  const int sl1 = sl0 + 16;
  const int sr = tid>>2;           // staging row (key for K, d for V)
  const int sc2 = (tid&3)*2;       // 16B-chunk pair index

  f32x4 oA[4], oB[4];
  #pragma unroll
  for (int i=0;i<4;i++){ oA[i]=(f32x4){0,0,0,0}; oB[i]=(f32x4){0,0,0,0}; }
  float MA=-INFINITY, LA=0.f, MB=-INFINITY, LB=0.f;
  s16x8 sk0, sk1, sv0, sv1;
  float4 pmv[4];

  // prologue: stage tile 0 into buf0
  STAGEISSUE(0);
  STAGEWRITE(Kl0, Vl0);
  __syncthreads();

  #pragma unroll 1
  for (int p=0; p<12; p++){
    const int t0 = p*128;
    TILE(Kl0,Vl0, t0,      1, t0+64,   Kl1,Vl1);
    TILE(Kl1,Vl1, t0+64,   1, t0+128,  Kl0,Vl0);
  }
  TILE(Kl0,Vl0, 1536, 0, 0, Kl0,Vl0);   // tail tile (32 valid keys; rest masked by policy pad)

  if (qA < N_){
    float inv = 1.f / (LA + EPS_);
    ushort* aop = AO + ((size_t)b*N_ + qA)*C_ + h*64 + 4*g;
    #pragma unroll
    for (int fd=0; fd<4; fd++){
      s16x4 r;
      r[0]=(short)f2bf(oA[fd][0]*inv); r[1]=(short)f2bf(oA[fd][1]*inv);
      r[2]=(short)f2bf(oA[fd][2]*inv); r[3]=(short)f2bf(oA[fd][3]*inv);
      *(s16x4*)(aop + fd*16) = r;
    }
  }
  if (qB < N_){
    float inv = 1.f / (LB + EPS_);
    ushort* aop = AO + ((size_t)b*N_ + qB)*C_ + h*64 + 4*g;
    #pragma unroll
    for (int fd=0; fd<4; fd++){
      s16x4 r;
      r[0]=(short)f2bf(oB[fd][0]*inv); r[1]=(short)f2bf(oB[fd][1]*inv);
      r[2]=(short)f2bf(oB[fd][2]*inv); r[3]=(short)f2bf(oB[fd][3]*inv);
      *(s16x4*)(aop + fd*16) = r;
    }
  }
}

// ---------------- proj GEMM (bf16, LDS-staged, 128x128 tile): out = AO @ Wpb^T + b, f32 out ----------------
__global__ __launch_bounds__(256) void proj_gemm(const ushort* __restrict__ A, const ushort* __restrict__ Wb,
                                                 const float* __restrict__ bias, float* __restrict__ out){
  __shared__ __align__(16) ushort Al[128*40];
  __shared__ __align__(16) ushort Bl[128*40];
  const int tid = threadIdx.x, lane = tid&63, w = tid>>6;
  const int g = lane>>4, lr = lane&15;
  const int wr = w>>1, wc = w&1;
  const int m0 = blockIdx.x*128, j0 = blockIdx.y*128;
  const int ar = tid>>1, ah = tid&1;
  f32x4 acc[4][4];
  #pragma unroll
  for (int i=0;i<4;i++)
    #pragma unroll
    for (int j=0;j<4;j++) acc[i][j]=(f32x4){0,0,0,0};

  for (int ks=0; ks<384; ks+=32){
    const ushort* as = A + (size_t)(m0+ar)*384 + ks + ah*16;
    s16x8 a0 = ((const s16x8*)as)[0];
    s16x8 a1 = ((const s16x8*)as)[1];
    const ushort* bs = Wb + (size_t)(j0+ar)*384 + ks + ah*16;
    s16x8 b0 = ((const s16x8*)bs)[0];
    s16x8 b1 = ((const s16x8*)bs)[1];
    *(s16x8*)&Al[ar*40 + ah*16]     = a0;
    *(s16x8*)&Al[ar*40 + ah*16 + 8] = a1;
    *(s16x8*)&Bl[ar*40 + ah*16]     = b0;
    *(s16x8*)&Bl[ar*40 + ah*16 + 8] = b1;
    __syncthreads();
    s16x8 af[4], bf[4];
    #pragma unroll
    for (int fm=0; fm<4; fm++) af[fm] = *(const s16x8*)&Al[(wr*64+fm*16+lr)*40 + g*8];
    #pragma unroll
    for (int fn=0; fn<4; fn++) bf[fn] = *(const s16x8*)&Bl[(wc*64+fn*16+lr)*40 + g*8];
    #pragma unroll
    for (int fm=0; fm<4; fm++)
      #pragma unroll
      for (int fn=0; fn<4; fn++)
        acc[fm][fn] = MFMA16(af[fm], bf[fn], acc[fm][fn]);
    __syncthreads();
  }
  float bsv[4];
  #pragma unroll
  for (int fn=0; fn<4; fn++) bsv[fn] = bias[j0 + wc*64 + fn*16 + lr];
  #pragma unroll
  for (int fm=0; fm<4; fm++){
    #pragma unroll
    for (int jj=0; jj<4; jj++){
      int m = m0 + wr*64 + fm*16 + g*4 + jj;
      #pragma unroll
      for (int fn=0; fn<4; fn++){
        int j = j0 + wc*64 + fn*16 + lr;
        out[(size_t)m*384 + j] = acc[fm][fn][jj] + bsv[fn];
      }
    }
  }
}

extern "C" void kernel_launch(void* const* d_in, const int* in_sizes, int n_in,
                              void* d_out, int out_size, void* d_ws, size_t ws_size,
                              hipStream_t stream) {
  const float* x     = (const float*)d_in[0];
  const float* vis   = (const float*)d_in[1];
  const float* wqkv  = (const float*)d_in[2];
  const float* wproj = (const float*)d_in[3];
  const float* bproj = (const float*)d_in[4];
  float* out = (float*)d_out;

  // Layout (tr path): Qg | Kg | Vtg | AO/Xb | Vg | Wqb | Wpb | pol
  ushort* Qg  = (ushort*)d_ws;
  ushort* Kg  = Qg + SZ_;
  ushort* Vtg = Kg + SZ_;
  ushort* AO  = Vtg + SZ_;         // aliased: Xb during qkv phase, AO afterwards
  ushort* Xb  = AO;
  ushort* Vg  = AO + SZ_;          // 5th buffer (only used on tr path)
  size_t need_tr = (size_t)5*SZ_*2 + (size_t)(3*C_*C_ + C_*C_)*2 + (size_t)POLPAD_*4;
  int tr = (ws_size >= need_tr) ? 1 : 0;
  ushort* Wqb = tr ? (Vg + SZ_) : (Vg);          // without tr, Vg slot unused -> weights move up
  ushort* Wpb = Wqb + 3*C_*C_;
  float*  pol_pad = (float*)(Wpb + C_*C_);

  cvt_pol<<<2690, 256, 0, stream>>>(x, wqkv, wproj, vis, Xb, Wqb, Wpb, pol_pad);
  qkv_gemm<<<dim3(98,9), 256, 0, stream>>>(Xb, Wqb, Qg, Kg, Vg, Vtg, tr);
  if (tr) v_tr<<<dim3(48,49), 256, 0, stream>>>(Vg, Vtg);
  attn_fwd<<<624, 256, 0, stream>>>(Qg, Kg, Vtg, pol_pad, AO);
  proj_gemm<<<dim3(98,3), 256, 0, stream>>>(AO, Wpb, bproj, out);
}

// Round 12
// 219.577 us; speedup vs baseline: 1.4355x; 1.0124x over previous
//
#include <hip/hip_runtime.h>

#define B_ 8
#define N_ 1568
#define NPAD_ 1600
#define C_ 384
#define H_ 6
#define D_ 64
#define BH_ 48
#define SZ_ (B_*H_*N_*D_)
#define EPS_ 1e-6f
#define CSC_ 0.18033688011112042f  /* D^-0.5 * log2(e) */

typedef short s16x8 __attribute__((ext_vector_type(8)));
typedef short s16x4 __attribute__((ext_vector_type(4)));
typedef float f32x4 __attribute__((ext_vector_type(4)));

static __device__ __forceinline__ ushort f2bf(float f){
  union { float f; unsigned u; } v; v.f = f;
  unsigned r = v.u + 0x7fffu + ((v.u >> 16) & 1u);
  return (ushort)(r >> 16);
}
static __device__ __forceinline__ unsigned cvtpk(float lo, float hi){
  unsigned r;
  asm("v_cvt_pk_bf16_f32 %0, %1, %2" : "=v"(r) : "v"(lo), "v"(hi));
  return r;
}
#define MFMA16(a,b,c) __builtin_amdgcn_mfma_f32_16x16x32_bf16((a),(b),(c),0,0,0)

#if __has_builtin(__builtin_amdgcn_exp2f)
#define EXP2F(x) __builtin_amdgcn_exp2f(x)
#else
#define EXP2F(x) exp2f(x)
#endif

// ---------------- convert f32 -> bf16 for X, w_qkv, w_proj + policy pad, one launch ----------------
#define XV8_ 602112   /* 12544*384/8 */
#define WQ8_ 55296    /* 1152*384/8 */
#define WP8_ 18432    /* 384*384/8  */
#define TOT8_ (XV8_+WQ8_+WP8_)
#define POLPAD_ (B_*NPAD_)
__global__ __launch_bounds__(256) void cvt_pol(const float* __restrict__ X, const float* __restrict__ Wq,
                                               const float* __restrict__ Wp, const float* __restrict__ vis,
                                               ushort* __restrict__ Xb, ushort* __restrict__ Wqb,
                                               ushort* __restrict__ Wpb, float* __restrict__ pp){
  int i = blockIdx.x*256 + threadIdx.x;
  if (i < TOT8_){
    const float* src; ushort* dst; int off;
    if (i < XV8_)            { src = X;  dst = Xb;  off = i; }
    else if (i < XV8_+WQ8_)  { src = Wq; dst = Wqb; off = i - XV8_; }
    else                     { src = Wp; dst = Wpb; off = i - XV8_ - WQ8_; }
    float4 a = ((const float4*)src)[off*2];
    float4 b = ((const float4*)src)[off*2+1];
    s16x8 r;
    r[0]=(short)f2bf(a.x); r[1]=(short)f2bf(a.y); r[2]=(short)f2bf(a.z); r[3]=(short)f2bf(a.w);
    r[4]=(short)f2bf(b.x); r[5]=(short)f2bf(b.y); r[6]=(short)f2bf(b.z); r[7]=(short)f2bf(b.w);
    *(s16x8*)&dst[off*8] = r;
  } else {
    int p = i - TOT8_;
    if (p < POLPAD_){
      int b = p / NPAD_, n = p - b*NPAD_;
      pp[p] = (n < N_) ? vis[b*N_ + n] : 0.f;
    }
  }
}

// ---------------- QKV GEMM (bf16, LDS-staged, 128x128 tile): qkv = Xb @ Wqb^T ----------------
__global__ __launch_bounds__(256) void qkv_gemm(const ushort* __restrict__ Xb, const ushort* __restrict__ Wb,
                                                ushort* __restrict__ Qg, ushort* __restrict__ Kg,
                                                ushort* __restrict__ Vg, ushort* __restrict__ Vtg,
                                                int vmode){
  __shared__ __align__(16) ushort Al[128*40];
  __shared__ __align__(16) ushort Bl[128*40];
  const int tid = threadIdx.x, lane = tid&63, w = tid>>6;
  const int g = lane>>4, lr = lane&15;
  const int wr = w>>1, wc = w&1;
  const int m0 = blockIdx.x*128, j0 = blockIdx.y*128;
  const int ar = tid>>1, ah = tid&1;
  f32x4 acc[4][4];
  #pragma unroll
  for (int i=0;i<4;i++)
    #pragma unroll
    for (int j=0;j<4;j++) acc[i][j]=(f32x4){0,0,0,0};

  for (int ks=0; ks<384; ks+=32){
    const ushort* as = Xb + (size_t)(m0+ar)*384 + ks + ah*16;
    s16x8 a0 = ((const s16x8*)as)[0];
    s16x8 a1 = ((const s16x8*)as)[1];
    const ushort* bs = Wb + (size_t)(j0+ar)*384 + ks + ah*16;
    s16x8 b0 = ((const s16x8*)bs)[0];
    s16x8 b1 = ((const s16x8*)bs)[1];
    *(s16x8*)&Al[ar*40 + ah*16]     = a0;
    *(s16x8*)&Al[ar*40 + ah*16 + 8] = a1;
    *(s16x8*)&Bl[ar*40 + ah*16]     = b0;
    *(s16x8*)&Bl[ar*40 + ah*16 + 8] = b1;
    __syncthreads();
    s16x8 af[4], bf[4];
    #pragma unroll
    for (int fm=0; fm<4; fm++) af[fm] = *(const s16x8*)&Al[(wr*64+fm*16+lr)*40 + g*8];
    #pragma unroll
    for (int fn=0; fn<4; fn++) bf[fn] = *(const s16x8*)&Bl[(wc*64+fn*16+lr)*40 + g*8];
    #pragma unroll
    for (int fm=0; fm<4; fm++)
      #pragma unroll
      for (int fn=0; fn<4; fn++)
        acc[fm][fn] = MFMA16(af[fm], bf[fn], acc[fm][fn]);
    __syncthreads();
  }
  #pragma unroll
  for (int fm=0; fm<4; fm++){
    #pragma unroll
    for (int jj=0; jj<4; jj++){
      int m = m0 + wr*64 + fm*16 + g*4 + jj;
      int bi = m / N_; int n = m - bi*N_;
      #pragma unroll
      for (int fn=0; fn<4; fn++){
        int j = j0 + wc*64 + fn*16 + lr;
        int t = j/384, jc = j - t*384;
        int h = jc>>6, d = jc&63;
        float v = acc[fm][fn][jj];
        if (t==0)      Qg[((size_t)(bi*H_+h)*N_ + n)*64 + d] = f2bf(v * CSC_);
        else if (t==1) Kg[((size_t)(bi*H_+h)*N_ + n)*64 + d] = f2bf(v);
        else {
          if (vmode) Vg[((size_t)(bi*H_+h)*N_ + n)*64 + d] = f2bf(v);
          else       Vtg[((size_t)(bi*H_+h)*64 + d)*N_ + n] = f2bf(v);
        }
      }
    }
  }
}

// ---------------- V transpose: Vg[bh][n][d] -> Vt[bh][d][n], LDS-staged, coalesced both sides ----------------
__global__ __launch_bounds__(256) void v_tr(const ushort* __restrict__ Vg, ushort* __restrict__ Vt){
  __shared__ ushort lds[32*72];
  const int bh = blockIdx.x, k0 = blockIdx.y*32;
  const int tid = threadIdx.x;
  const int r = tid>>3, dc = (tid&7)*8;
  *(s16x8*)&lds[r*72 + dc] = *(const s16x8*)&Vg[((size_t)bh*N_ + k0 + r)*64 + dc];
  __syncthreads();
  const int d = tid>>2, kc = (tid&3)*8;
  s16x8 o;
  #pragma unroll
  for (int i=0;i<8;i++) o[i] = (short)lds[(kc+i)*72 + d];
  *(s16x8*)&Vt[((size_t)bh*64 + d)*N_ + k0 + kc] = o;
}

// ---------------- fused flash attention: 4-wave blocks, 16 q-rows/wave, KVBLK=64 dbuf LDS ----------------
#define LDST_ 72   /* LDS row stride (elements): 144B, chunk stride 9 (odd) */

#define LOADP(TT) do{ \
  _Pragma("unroll") \
  for (int kg=0;kg<4;kg++) pmv[kg] = *(const float4*)&polp[(TT) + kg*16 + 4*g]; }while(0)

#define STAGEISSUE(T0N) do{ \
  int kr_ = (T0N)+sr; kr_ = kr_<N_?kr_:N_-1; \
  const ushort* kp_ = Kbh + (size_t)kr_*64 + sc2*8; \
  sk0 = *(const s16x8*)(kp_); sk1 = *(const s16x8*)(kp_+8); \
  const ushort* vp_ = Vbh + (size_t)sr*N_ + (T0N) + sc2*8; \
  sv0 = *(const s16x8*)(vp_); sv1 = *(const s16x8*)(vp_+8); \
}while(0)

#define STAGEWRITE(KD,VD) do{ \
  *(s16x8*)&(KD)[sr*LDST_ + sc2*8]     = sk0; \
  *(s16x8*)&(KD)[sr*LDST_ + sc2*8 + 8] = sk1; \
  *(s16x8*)&(VD)[sr*LDST_ + sc2*8]     = sv0; \
  *(s16x8*)&(VD)[sr*LDST_ + sc2*8 + 8] = sv1; }while(0)

#define PROCQ(KB,VB,QF0,QF1,OO,MM,LL,QQ,DG,T0) do{ \
  f32x4 st[4]; \
  __builtin_amdgcn_s_setprio(1); \
  _Pragma("unroll") \
  for (int kg=0;kg<4;kg++){ \
    const ushort* krp_ = (KB) + (kg*16+lr)*LDST_ + g*8; \
    s16x8 kf0_ = *(const s16x8*)(krp_); \
    s16x8 kf1_ = *(const s16x8*)(krp_+32); \
    f32x4 z=(f32x4){0,0,0,0}; z=MFMA16(kf0_,QF0,z); st[kg]=MFMA16(kf1_,QF1,z); } \
  __builtin_amdgcn_s_setprio(0); \
  float pmax; { \
    float x0=fmaxf(fmaxf(st[0][0],st[0][1]),fmaxf(st[0][2],st[0][3])); \
    float x1=fmaxf(fmaxf(st[1][0],st[1][1]),fmaxf(st[1][2],st[1][3])); \
    float x2=fmaxf(fmaxf(st[2][0],st[2][1]),fmaxf(st[2][2],st[2][3])); \
    float x3=fmaxf(fmaxf(st[3][0],st[3][1]),fmaxf(st[3][2],st[3][3])); \
    pmax=fmaxf(fmaxf(x0,x1),fmaxf(x2,x3)); \
    pmax=fmaxf(pmax,__shfl_xor(pmax,16)); pmax=fmaxf(pmax,__shfl_xor(pmax,32)); } \
  if (__any(pmax > (MM)+8.f)){ \
    float Mn=fmaxf((MM),pmax); float corr=EXP2F((MM)-Mn); (LL)*=corr; \
    _Pragma("unroll") for (int fd=0;fd<4;fd++){ OO[fd][0]*=corr;OO[fd][1]*=corr;OO[fd][2]*=corr;OO[fd][3]*=corr; } \
    (MM)=Mn; } \
  _Pragma("unroll") \
  for (int kg=0;kg<4;kg++){ \
    _Pragma("unroll") \
    for (int jj=0;jj<4;jj++){ \
      float e=EXP2F(st[kg][jj]-(MM)); float em=e*((&pmv[kg].x)[jj]); \
      int key=(T0)+kg*16+4*g+jj; \
      st[kg][jj]=((DG)&&key==(QQ))?e:em; } } \
  { float se=(st[0][0]+st[0][1])+(st[0][2]+st[0][3]); \
    se+=(st[1][0]+st[1][1])+(st[1][2]+st[1][3]); \
    se+=(st[2][0]+st[2][1])+(st[2][2]+st[2][3]); \
    se+=(st[3][0]+st[3][1])+(st[3][2]+st[3][3]); \
    se+=__shfl_xor(se,16); se+=__shfl_xor(se,32); (LL)+=se; } \
  unsigned pk[4][2]; \
  _Pragma("unroll") \
  for (int kg=0;kg<4;kg++){ pk[kg][0]=cvtpk(st[kg][0],st[kg][1]); pk[kg][1]=cvtpk(st[kg][2],st[kg][3]); } \
  union { unsigned u[4]; s16x8 v; } bfr[2]; \
  _Pragma("unroll") \
  for (int kh=0;kh<2;kh++){ \
    _Pragma("unroll") \
    for (int wd=0;wd<4;wd++){ \
      int srcl=(wd<2)?sl0:sl1; \
      unsigned q0_=(unsigned)__shfl((int)pk[2*kh][wd&1],srcl); \
      unsigned q1_=(unsigned)__shfl((int)pk[2*kh+1][wd&1],srcl); \
      bfr[kh].u[wd]=(g<2)?q0_:q1_; } } \
  __builtin_amdgcn_s_setprio(1); \
  _Pragma("unroll") \
  for (int fd=0;fd<4;fd++){ \
    const ushort* vrp_ = (VB) + (fd*16+lr)*LDST_ + g*8; \
    s16x8 va0_ = *(const s16x8*)(vrp_); \
    s16x8 va1_ = *(const s16x8*)(vrp_+32); \
    OO[fd]=MFMA16(va0_,bfr[0].v,OO[fd]); OO[fd]=MFMA16(va1_,bfr[1].v,OO[fd]); } \
  __builtin_amdgcn_s_setprio(0); \
}while(0)

#define TILE(KB,VB,T0,STG,T0N,KD,VD) do{ \
  if (STG){ STAGEISSUE(T0N); __builtin_amdgcn_sched_barrier(0); } \
  LOADP(T0); \
  const bool dg_ = (dtile == (T0)); \
  PROCQ(KB,VB, qa0,qa1, oA,MA,LA,qA, dg_, T0); \
  if (STG){ STAGEWRITE(KD,VD); __syncthreads(); } \
}while(0)

__global__ __launch_bounds__(256,4) void attn_fwd(const ushort* __restrict__ Qg, const ushort* __restrict__ Kg,
                                                  const ushort* __restrict__ Vt, const float* __restrict__ pol,
                                                  ushort* __restrict__ AO){
  __shared__ __align__(16) ushort Kl0[64*LDST_], Kl1[64*LDST_];
  __shared__ __align__(16) ushort Vl0[64*LDST_], Vl1[64*LDST_];
  const int tid = threadIdx.x, lane = tid&63, w = tid>>6;
  const int g = lane>>4, lr = lane&15;
  // XCD-chunked swizzle: 1200 = 8 XCDs x 150; each XCD gets 6 consecutive bh's (25 qb each)
  const int orig = blockIdx.x;
  const int wg = (orig & 7)*150 + (orig >> 3);
  const int bh = wg / 25, qb = wg - bh*25;
  const int b = bh / H_, h = bh - b*H_;
  const int dtile = qb*64;                 // diagonal key tile for this block
  const int qA = dtile + w*16 + lr;        // 16 q-rows per wave
  const int qAc = qA < N_ ? qA : N_-1;
  const ushort* QrA = Qg + ((size_t)bh*N_ + qAc)*64;
  const s16x8 qa0 = *(const s16x8*)(QrA + g*8);
  const s16x8 qa1 = *(const s16x8*)(QrA + 32 + g*8);
  const float* polp = pol + b*NPAD_;
  const ushort* Kbh = Kg + (size_t)bh*N_*64;
  const ushort* Vbh = Vt + (size_t)bh*64*N_;
  const int sl0 = ((lane>>4)&1)<<5 | lr;
  const int sl1 = sl0 + 16;
  const int sr = tid>>2;           // staging row (key for K, d for V)
  const int sc2 = (tid&3)*2;       // 16B-chunk pair index

  f32x4 oA[4];
  #pragma unroll
  for (int i=0;i<4;i++) oA[i]=(f32x4){0,0,0,0};
  float MA=-INFINITY, LA=0.f;
  s16x8 sk0, sk1, sv0, sv1;
  float4 pmv[4];

  // prologue: stage tile 0 into buf0
  STAGEISSUE(0);
  STAGEWRITE(Kl0, Vl0);
  __syncthreads();

  #pragma unroll 1
  for (int p=0; p<12; p++){
    const int t0 = p*128;
    TILE(Kl0,Vl0, t0,      1, t0+64,   Kl1,Vl1);
    TILE(Kl1,Vl1, t0+64,   1, t0+128,  Kl0,Vl0);
  }
  TILE(Kl0,Vl0, 1536, 0, 0, Kl0,Vl0);   // tail tile (32 valid keys; rest masked by policy pad)

  if (qA < N_){
    float inv = 1.f / (LA + EPS_);
    ushort* aop = AO + ((size_t)b*N_ + qA)*C_ + h*64 + 4*g;
    #pragma unroll
    for (int fd=0; fd<4; fd++){
      s16x4 r;
      r[0]=(short)f2bf(oA[fd][0]*inv); r[1]=(short)f2bf(oA[fd][1]*inv);
      r[2]=(short)f2bf(oA[fd][2]*inv); r[3]=(short)f2bf(oA[fd][3]*inv);
      *(s16x4*)(aop + fd*16) = r;
    }
  }
}

// ---------------- proj GEMM (bf16, LDS-staged, 128x128 tile): out = AO @ Wpb^T + b, f32 out ----------------
__global__ __launch_bounds__(256) void proj_gemm(const ushort* __restrict__ A, const ushort* __restrict__ Wb,
                                                 const float* __restrict__ bias, float* __restrict__ out){
  __shared__ __align__(16) ushort Al[128*40];
  __shared__ __align__(16) ushort Bl[128*40];
  const int tid = threadIdx.x, lane = tid&63, w = tid>>6;
  const int g = lane>>4, lr = lane&15;
  const int wr = w>>1, wc = w&1;
  const int m0 = blockIdx.x*128, j0 = blockIdx.y*128;
  const int ar = tid>>1, ah = tid&1;
  f32x4 acc[4][4];
  #pragma unroll
  for (int i=0;i<4;i++)
    #pragma unroll
    for (int j=0;j<4;j++) acc[i][j]=(f32x4){0,0,0,0};

  for (int ks=0; ks<384; ks+=32){
    const ushort* as = A + (size_t)(m0+ar)*384 + ks + ah*16;
    s16x8 a0 = ((const s16x8*)as)[0];
    s16x8 a1 = ((const s16x8*)as)[1];
    const ushort* bs = Wb + (size_t)(j0+ar)*384 + ks + ah*16;
    s16x8 b0 = ((const s16x8*)bs)[0];
    s16x8 b1 = ((const s16x8*)bs)[1];
    *(s16x8*)&Al[ar*40 + ah*16]     = a0;
    *(s16x8*)&Al[ar*40 + ah*16 + 8] = a1;
    *(s16x8*)&Bl[ar*40 + ah*16]     = b0;
    *(s16x8*)&Bl[ar*40 + ah*16 + 8] = b1;
    __syncthreads();
    s16x8 af[4], bf[4];
    #pragma unroll
    for (int fm=0; fm<4; fm++) af[fm] = *(const s16x8*)&Al[(wr*64+fm*16+lr)*40 + g*8];
    #pragma unroll
    for (int fn=0; fn<4; fn++) bf[fn] = *(const s16x8*)&Bl[(wc*64+fn*16+lr)*40 + g*8];
    #pragma unroll
    for (int fm=0; fm<4; fm++)
      #pragma unroll
      for (int fn=0; fn<4; fn++)
        acc[fm][fn] = MFMA16(af[fm], bf[fn], acc[fm][fn]);
    __syncthreads();
  }
  float bsv[4];
  #pragma unroll
  for (int fn=0; fn<4; fn++) bsv[fn] = bias[j0 + wc*64 + fn*16 + lr];
  #pragma unroll
  for (int fm=0; fm<4; fm++){
    #pragma unroll
    for (int jj=0; jj<4; jj++){
      int m = m0 + wr*64 + fm*16 + g*4 + jj;
      #pragma unroll
      for (int fn=0; fn<4; fn++){
        int j = j0 + wc*64 + fn*16 + lr;
        out[(size_t)m*384 + j] = acc[fm][fn][jj] + bsv[fn];
      }
    }
  }
}

extern "C" void kernel_launch(void* const* d_in, const int* in_sizes, int n_in,
                              void* d_out, int out_size, void* d_ws, size_t ws_size,
                              hipStream_t stream) {
  const float* x     = (const float*)d_in[0];
  const float* vis   = (const float*)d_in[1];
  const float* wqkv  = (const float*)d_in[2];
  const float* wproj = (const float*)d_in[3];
  const float* bproj = (const float*)d_in[4];
  float* out = (float*)d_out;

  // Layout (tr path): Qg | Kg | Vtg | AO/Xb | Vg | Wqb | Wpb | pol
  ushort* Qg  = (ushort*)d_ws;
  ushort* Kg  = Qg + SZ_;
  ushort* Vtg = Kg + SZ_;
  ushort* AO  = Vtg + SZ_;         // aliased: Xb during qkv phase, AO afterwards
  ushort* Xb  = AO;
  ushort* Vg  = AO + SZ_;          // 5th buffer (only used on tr path)
  size_t need_tr = (size_t)5*SZ_*2 + (size_t)(3*C_*C_ + C_*C_)*2 + (size_t)POLPAD_*4;
  int tr = (ws_size >= need_tr) ? 1 : 0;
  ushort* Wqb = tr ? (Vg + SZ_) : (Vg);          // without tr, Vg slot unused -> weights move up
  ushort* Wpb = Wqb + 3*C_*C_;
  float*  pol_pad = (float*)(Wpb + C_*C_);

  cvt_pol<<<2690, 256, 0, stream>>>(x, wqkv, wproj, vis, Xb, Wqb, Wpb, pol_pad);
  qkv_gemm<<<dim3(98,9), 256, 0, stream>>>(Xb, Wqb, Qg, Kg, Vg, Vtg, tr);
  if (tr) v_tr<<<dim3(48,49), 256, 0, stream>>>(Vg, Vtg);
  attn_fwd<<<1200, 256, 0, stream>>>(Qg, Kg, Vtg, pol_pad, AO);
  proj_gemm<<<dim3(98,3), 256, 0, stream>>>(AO, Wpb, bproj, out);
}